// Round 6
// baseline (5277.131 us; speedup 1.0000x reference)
//
#include <hip/hip_runtime.h>
#include <hip/hip_cooperative_groups.h>
#include <math.h>

namespace cg = cooperative_groups;

#define BATCHN 256
#define HDIM 512
#define ZDIM 128
#define NGRID 32
#define ABDIM 128
#define IMGSZ 16384   // 128*128
#define ENCIN 2560
#define G3 1536
#define SLAB (BATCHN*G3)      // 393216 floats per partial slab

typedef __attribute__((ext_vector_type(8))) short short8;
typedef __attribute__((ext_vector_type(4))) float f32x4;

__device__ __forceinline__ float sigmoidf_(float x){ return 1.0f/(1.0f+expf(-x)); }

__device__ __forceinline__ ushort f2bf_rne(float f){
    union{float f; uint u;} x; x.f=f;
    uint r = (x.u + 0x7FFFu + ((x.u>>16)&1u)) >> 16;
    return (ushort)r;
}
__device__ __forceinline__ float bf2f(ushort h){
    union{uint u; float f;} y; y.u = ((uint)h)<<16;
    return y.f;
}

__global__ void init_slast_k(float* __restrict__ s_last){
    int i = blockIdx.x*256 + threadIdx.x;
    s_last[i] = 0.5f;   // sigmoid(0)
}

// convert f32 weights -> bf16 hi/lo arrays (vector-4)
__global__ void conv_w_k(const float* __restrict__ W, ushort* __restrict__ Wh,
                         ushort* __restrict__ Wl, int n4){
    int i = blockIdx.x*256 + threadIdx.x;
    if(i>=n4) return;
    float4 v = ((const float4*)W)[i];
    float f[4] = {v.x, v.y, v.z, v.w};
    ushort h[4], l[4];
    #pragma unroll
    for(int j=0;j<4;j++){
        h[j] = f2bf_rne(f[j]);
        l[j] = f2bf_rne(f[j] - bf2f(h[j]));
    }
    ushort4 hv; hv.x=h[0]; hv.y=h[1]; hv.z=h[2]; hv.w=h[3];
    ushort4 lv; lv.x=l[0]; lv.y=l[1]; lv.z=l[2]; lv.w=l[3];
    ((ushort4*)Wh)[i] = hv;
    ((ushort4*)Wl)[i] = lv;
}

// ---- attention params, 512 threads; pp[0..4] = raw p vector ----
__device__ void attn_params_dev(const float* __restrict__ h,
        const float* __restrict__ W, const float* __restrict__ bvec,
        float* red5 /*[40]*/, float* pp /*[8]*/, int tid){
    float accp[5];
    #pragma unroll
    for(int i=0;i<5;i++) accp[i]=0.f;
    for(int k=tid;k<HDIM;k+=512){
        float hv = h[k];
        #pragma unroll
        for(int i=0;i<5;i++) accp[i] += hv*W[i*HDIM+k];
    }
    int wv = tid>>6;
    #pragma unroll
    for(int i=0;i<5;i++){
        float a = accp[i];
        #pragma unroll
        for(int o=32;o>0;o>>=1) a += __shfl_down(a,o);
        if((tid&63)==0) red5[i*8+wv]=a;
    }
    __syncthreads();
    if(tid<5){
        float s = bvec[tid];
        #pragma unroll
        for(int w2=0;w2<8;w2++) s += red5[tid*8+w2];
        pp[tid]=s;
    }
    __syncthreads();
}

// transposed fill: fxT[pix*32+j], fyT[pix*32+j]; 512 threads
__device__ void fill_fb_T(float* fxT, float* fyT, const float* pp, int tid){
    float gx = 64.5f*(pp[0]+1.0f);
    float gy = 64.5f*(pp[1]+1.0f);
    float tss = 2.0f*expf(pp[2]);
    float delta = (127.0f/31.0f)*expf(pp[3]);
    int rr = tid>>3;
    int q  = tid&7;
    int j  = rr&31;
    bool isY = rr>=32;
    float mu = (isY?gy:gx) + ((float)j-15.5f)*delta;
    float v[16]; float s=0.f;
    #pragma unroll
    for(int i=0;i<16;i++){
        float d = (float)(q*16+i)-mu;
        float e = expf(-d*d/tss);
        v[i]=e; s+=e;
    }
    s += __shfl_xor(s,1); s += __shfl_xor(s,2); s += __shfl_xor(s,4);
    float inv = 1.0f/fmaxf(s,1e-8f);
    float* dst = isY? fyT : fxT;
    #pragma unroll
    for(int i=0;i<16;i++) dst[(q*16+i)*32 + j] = v[i]*inv;
    __syncthreads();
}

// row-major fill: fx/fy stride 129; 512 threads
__device__ void fill_fb_R(float* fx, float* fy, const float* pp, int tid){
    float gx = 64.5f*(pp[0]+1.0f);
    float gy = 64.5f*(pp[1]+1.0f);
    float tss = 2.0f*expf(pp[2]);
    float delta = (127.0f/31.0f)*expf(pp[3]);
    int rr = tid>>3;
    int q  = tid&7;
    int j  = rr&31;
    bool isY = rr>=32;
    float mu = (isY?gy:gx) + ((float)j-15.5f)*delta;
    float v[16]; float s=0.f;
    #pragma unroll
    for(int i=0;i<16;i++){
        float d = (float)(q*16+i)-mu;
        float e = expf(-d*d/tss);
        v[i]=e; s+=e;
    }
    s += __shfl_xor(s,1); s += __shfl_xor(s,2); s += __shfl_xor(s,4);
    float inv = 1.0f/fmaxf(s,1e-8f);
    float* rowp = (isY? fy : fx) + j*129;
    #pragma unroll
    for(int i=0;i<16;i++) rowp[q*16+i] = v[i]*inv;
    __syncthreads();
}

// ---- one MFMA GEMM job: 128x64 tile, 8 waves, BK=64, split-bf16 (3 products) ----
__device__ void gemm_job(const ushort* __restrict__ Agh, const ushort* __restrict__ Agl,
        const ushort* __restrict__ Wh, const ushort* __restrict__ Wl,
        int K, int k0, int kiters, int row0, int col0, int Nn, float* __restrict__ Out,
        ushort* AH, ushort* AL, ushort* BH, ushort* BL, int tid){
    int lane = tid&63, w = tid>>6;
    int m0 = (w>>1)*32, n0 = (w&1)*32;
    int fr = lane&15, kq = (lane>>4)*8;
    int rA = tid>>2, kA = (tid&3)*16;
    int rB = tid>>3, kB = (tid&7)*8;
    f32x4 acc[2][2];
    #pragma unroll
    for(int i=0;i<2;i++)
        #pragma unroll
        for(int j=0;j<2;j++) acc[i][j]=(f32x4){0.f,0.f,0.f,0.f};
    for(int it=0; it<kiters; ++it){
        int kb = k0 + it*64;
        size_t aoff = (size_t)(row0+rA)*K + kb + kA;
        size_t boff = (size_t)(col0+rB)*K + kb + kB;
        uint4 ah0 = *(const uint4*)(Agh + aoff);
        uint4 ah1 = *(const uint4*)(Agh + aoff + 8);
        uint4 al0 = *(const uint4*)(Agl + aoff);
        uint4 al1 = *(const uint4*)(Agl + aoff + 8);
        uint4 bh0 = *(const uint4*)(Wh + boff);
        uint4 bl0 = *(const uint4*)(Wl + boff);
        __syncthreads();              // prior frag reads complete
        *(uint4*)&AH[rA*72 + kA]     = ah0;
        *(uint4*)&AH[rA*72 + kA + 8] = ah1;
        *(uint4*)&AL[rA*72 + kA]     = al0;
        *(uint4*)&AL[rA*72 + kA + 8] = al1;
        *(uint4*)&BH[rB*72 + kB]     = bh0;
        *(uint4*)&BL[rB*72 + kB]     = bl0;
        __syncthreads();
        #pragma unroll
        for(int ks=0; ks<2; ks++){
            int kk = ks*32 + kq;
            short8 a_h[2], a_l[2], b_h[2], b_l[2];
            #pragma unroll
            for(int mf=0;mf<2;mf++){
                a_h[mf] = *(short8*)&AH[(m0+mf*16+fr)*72 + kk];
                a_l[mf] = *(short8*)&AL[(m0+mf*16+fr)*72 + kk];
            }
            #pragma unroll
            for(int nf=0;nf<2;nf++){
                b_h[nf] = *(short8*)&BH[(n0+nf*16+fr)*72 + kk];
                b_l[nf] = *(short8*)&BL[(n0+nf*16+fr)*72 + kk];
            }
            #pragma unroll
            for(int mf=0;mf<2;mf++)
                #pragma unroll
                for(int nf=0;nf<2;nf++){
                    acc[mf][nf] = __builtin_amdgcn_mfma_f32_16x16x32_bf16(a_h[mf], b_h[nf], acc[mf][nf], 0,0,0);
                    acc[mf][nf] = __builtin_amdgcn_mfma_f32_16x16x32_bf16(a_h[mf], b_l[nf], acc[mf][nf], 0,0,0);
                    acc[mf][nf] = __builtin_amdgcn_mfma_f32_16x16x32_bf16(a_l[mf], b_h[nf], acc[mf][nf], 0,0,0);
                }
        }
    }
    int crow = (lane>>4)*4, ccol = lane&15;
    #pragma unroll
    for(int mf=0;mf<2;mf++)
        #pragma unroll
        for(int nf=0;nf<2;nf++)
            #pragma unroll
            for(int r=0;r<4;r++)
                Out[(size_t)(row0+m0+mf*16+crow+r)*Nn + col0+n0+nf*16+ccol] = acc[mf][nf][r];
}

struct MegaP {
    const float *x, *eps;
    const float *bie, *bhe, *bid_, *bhd;
    const float *Wmu, *bmu, *Wls, *bls;
    const float *bwr, *Wra, *bra, *Wwa, *bwa;
    float *rec, *h_enc, *h_dec, *s_last;
    const ushort *Wie_h,*Wie_l,*Whe_h,*Whe_l,*Wid_h,*Wid_l,*Whd_h,*Whd_l,*Wwr_h,*Wwr_l;
    ushort *Eh,*El,*He_h,*He_l,*Hd_h,*Hd_l,*Zh,*Zl;
    float *Pi,*Ph,*Ph2;
};

__global__ __launch_bounds__(512) void mega_k(MegaP P){
    cg::grid_group gg = cg::this_grid();
    __shared__ __align__(16) char smem_raw[57344];
    float*  smemF = (float*)smem_raw;
    ushort* smemU = (ushort*)smem_raw;
    ushort* AH = smemU;
    ushort* AL = smemU + 9216;
    ushort* BH = smemU + 18432;
    ushort* BL = smemU + 23040;
    int tid = threadIdx.x;
    int blk = blockIdx.x;
    float* Pw  = P.Pi + SLAB;       // aliases Pi slabs 1-3 (dead after PC)
    float* Pi2 = P.Pi;              // aliases Pi slab 0  (dead after PC)

    for(int t=0; t<16; ++t){
        const float* eps_t = P.eps + (size_t)t*BATCHN*ZDIM;
        // ================= PA: read attention (per-batch) =================
        {
            float* sFxT = smemF;
            float* sFyT = smemF + 4096;
            float* tmp  = smemF + 4096;     // aliases sFyT (barrier-separated)
            float* red5 = smemF + 12352;
            float* pp   = red5 + 40;
            int bb = blk;
            const float* h = P.h_dec + (size_t)bb*HDIM;
            attn_params_dev(h, P.Wra, P.bra, red5, pp, tid);
            float gamma = expf(pp[4]);
            fill_fb_T(sFxT, sFyT, pp, tid);
            const float* img = P.x + (size_t)bb*IMGSZ;
            int c = tid & 127;
            int jg = tid >> 7;
            float acc0[8], accS[8];
            #pragma unroll
            for(int i=0;i<8;i++){ acc0[i]=0.f; accS[i]=0.f; }
            for(int k=0;k<ABDIM;k++){
                float s  = img[k*ABDIM + c];
                float sl = P.s_last[k*ABDIM + c];
                float4 f0 = *(const float4*)&sFyT[k*32 + jg*8];
                float4 f1 = *(const float4*)&sFyT[k*32 + jg*8 + 4];
                acc0[0]+=f0.x*s;  acc0[1]+=f0.y*s;  acc0[2]+=f0.z*s;  acc0[3]+=f0.w*s;
                acc0[4]+=f1.x*s;  acc0[5]+=f1.y*s;  acc0[6]+=f1.z*s;  acc0[7]+=f1.w*s;
                accS[0]+=f0.x*sl; accS[1]+=f0.y*sl; accS[2]+=f0.z*sl; accS[3]+=f0.w*sl;
                accS[4]+=f1.x*sl; accS[5]+=f1.y*sl; accS[6]+=f1.z*sl; accS[7]+=f1.w*sl;
            }
            __syncthreads();
            #pragma unroll
            for(int i=0;i<8;i++){
                int j = jg*8+i;
                tmp[0*32*129 + j*129 + c] = acc0[i];
                tmp[1*32*129 + j*129 + c] = acc0[i] - accS[i];
            }
            __syncthreads();
            {
                int i4 = tid & 7;
                int j  = (tid>>3) & 31;
                int p  = tid >> 8;
                float a0=0.f,a1=0.f,a2=0.f,a3=0.f;
                for(int cc=0; cc<ABDIM; cc++){
                    float tv = tmp[p*32*129 + j*129 + cc];
                    float4 fx = *(const float4*)&sFxT[cc*32 + i4*4];
                    a0 += tv*fx.x; a1 += tv*fx.y; a2 += tv*fx.z; a3 += tv*fx.w;
                }
                float ov[4] = {gamma*a0, gamma*a1, gamma*a2, gamma*a3};
                ushort4 oh, ol; ushort hq;
                hq=f2bf_rne(ov[0]); oh.x=hq; ol.x=f2bf_rne(ov[0]-bf2f(hq));
                hq=f2bf_rne(ov[1]); oh.y=hq; ol.y=f2bf_rne(ov[1]-bf2f(hq));
                hq=f2bf_rne(ov[2]); oh.z=hq; ol.z=f2bf_rne(ov[2]-bf2f(hq));
                hq=f2bf_rne(ov[3]); oh.w=hq; ol.w=f2bf_rne(ov[3]-bf2f(hq));
                size_t off = (size_t)bb*ENCIN + p*1024 + j*NGRID + i4*4;
                *(ushort4*)(P.Eh + off) = oh;
                *(ushort4*)(P.El + off) = ol;
            }
            P.Eh[(size_t)bb*ENCIN + 2048 + tid] = P.Hd_h[(size_t)bb*HDIM + tid];
            P.El[(size_t)bb*ENCIN + 2048 + tid] = P.Hd_l[(size_t)bb*HDIM + tid];
        }
        gg.sync();
        // ====== PB: GEMMs — enc-i (240 jobs) + enc-h (96) + dec-h (96) ======
        for(int job=blk; job<432; job+=256){
            const ushort *Ah_,*Al_,*Wh_,*Wl_; int K_,k0_,ki_,r0_,c0_; float* Out_;
            if(job < 240){
                int tt2 = job % 48, s = job / 48;
                Ah_=P.Eh; Al_=P.El; Wh_=P.Wie_h; Wl_=P.Wie_l;
                K_=ENCIN; k0_=s*512; ki_=8;
                r0_=(tt2/24)*128; c0_=(tt2%24)*64;
                Out_ = P.Pi + (size_t)s*SLAB;
            } else if(job < 336){
                int jj = job-240; int tt2 = jj % 48, s = jj / 48;
                Ah_=P.He_h; Al_=P.He_l; Wh_=P.Whe_h; Wl_=P.Whe_l;
                K_=HDIM; k0_=s*256; ki_=4;
                r0_=(tt2/24)*128; c0_=(tt2%24)*64;
                Out_ = P.Ph + (size_t)s*SLAB;
            } else {
                int jj = job-336; int tt2 = jj % 48, s = jj / 48;
                Ah_=P.Hd_h; Al_=P.Hd_l; Wh_=P.Whd_h; Wl_=P.Whd_l;
                K_=HDIM; k0_=s*256; ki_=4;
                r0_=(tt2/24)*128; c0_=(tt2%24)*64;
                Out_ = P.Ph2 + (size_t)s*SLAB;
            }
            gemm_job(Ah_, Al_, Wh_, Wl_, K_, k0_, ki_, r0_, c0_, G3, Out_, AH, AL, BH, BL, tid);
        }
        gg.sync();
        // ========== PC: encoder combine + z sample (per-batch) ==========
        {
            float* hs = smemF;
            int bb = blk, j = tid;
            float gi_r=P.bie[j], gi_z=P.bie[512+j], gi_n=P.bie[1024+j];
            float gh_r=P.bhe[j], gh_z=P.bhe[512+j], gh_n=P.bhe[1024+j];
            #pragma unroll
            for(int s=0;s<5;s++){
                size_t base = (size_t)s*SLAB + (size_t)bb*G3 + j;
                gi_r += P.Pi[base]; gi_z += P.Pi[base+512]; gi_n += P.Pi[base+1024];
            }
            #pragma unroll
            for(int s=0;s<2;s++){
                size_t base = (size_t)s*SLAB + (size_t)bb*G3 + j;
                gh_r += P.Ph[base]; gh_z += P.Ph[base+512]; gh_n += P.Ph[base+1024];
            }
            float r = sigmoidf_(gi_r + gh_r);
            float z = sigmoidf_(gi_z + gh_z);
            float n = tanhf(gi_n + r*gh_n);
            size_t hoff = (size_t)bb*HDIM + j;
            float hn = (1.f - z)*n + z*P.h_enc[hoff];
            P.h_enc[hoff] = hn; hs[j] = hn;
            ushort hh = f2bf_rne(hn);
            P.He_h[hoff] = hh; P.He_l[hoff] = f2bf_rne(hn - bf2f(hh));
            __syncthreads();
            int jo = tid>>2, l4 = tid&3;
            float am=0.f, al_=0.f;
            for(int k=l4;k<HDIM;k+=4){
                float hv = hs[k];
                am  += hv*P.Wmu[(size_t)jo*HDIM+k];
                al_ += hv*P.Wls[(size_t)jo*HDIM+k];
            }
            am  += __shfl_xor(am,1);  am  += __shfl_xor(am,2);
            al_ += __shfl_xor(al_,1); al_ += __shfl_xor(al_,2);
            if(l4==0){
                float mu = am + P.bmu[jo];
                float sg = expf(al_ + P.bls[jo]);
                float zv = mu + eps_t[(size_t)bb*ZDIM + jo]*sg;
                ushort zh = f2bf_rne(zv);
                P.Zh[(size_t)bb*ZDIM + jo] = zh;
                P.Zl[(size_t)bb*ZDIM + jo] = f2bf_rne(zv - bf2f(zh));
            }
        }
        gg.sync();
        // ========== PD: dec-i GEMM (48 jobs) ==========
        if(blk < 48){
            int tt2 = blk;
            gemm_job(P.Zh, P.Zl, P.Wid_h, P.Wid_l, ZDIM, 0, 2,
                     (tt2/24)*128, (tt2%24)*64, G3, Pi2, AH, AL, BH, BL, tid);
        }
        gg.sync();
        // ========== PE: decoder combine (1 elem/thread) ==========
        {
            int idx = blk*512 + tid;
            int bb = idx>>9, j = idx&511;
            float gi_r=P.bid_[j], gi_z=P.bid_[512+j], gi_n=P.bid_[1024+j];
            float gh_r=P.bhd[j], gh_z=P.bhd[512+j], gh_n=P.bhd[1024+j];
            {
                size_t base = (size_t)bb*G3 + j;
                gi_r += Pi2[base]; gi_z += Pi2[base+512]; gi_n += Pi2[base+1024];
            }
            #pragma unroll
            for(int s=0;s<2;s++){
                size_t base = (size_t)s*SLAB + (size_t)bb*G3 + j;
                gh_r += P.Ph2[base]; gh_z += P.Ph2[base+512]; gh_n += P.Ph2[base+1024];
            }
            float r = sigmoidf_(gi_r + gh_r);
            float z = sigmoidf_(gi_z + gh_z);
            float n = tanhf(gi_n + r*gh_n);
            float hn = (1.f - z)*n + z*P.h_dec[idx];
            P.h_dec[idx] = hn;
            ushort hh = f2bf_rne(hn);
            P.Hd_h[idx] = hh; P.Hd_l[idx] = f2bf_rne(hn - bf2f(hh));
        }
        gg.sync();
        // ========== PF: write GEMM (128 jobs) ==========
        if(blk < 128){
            int tt2 = blk % 32, s = blk / 32;
            gemm_job(P.Hd_h, P.Hd_l, P.Wwr_h, P.Wwr_l, HDIM, s*128, 2,
                     (tt2/16)*128, (tt2%16)*64, 1024, Pw + (size_t)s*BATCHN*1024,
                     AH, AL, BH, BL, tid);
        }
        gg.sync();
        // ========== PG: write attention apply (per-batch) ==========
        {
            float* sFy  = smemF;              // 32x129
            float* sFx  = smemF + 4128;       // 32x129
            float* sw   = smemF + 8256;       // 32x36
            float* tt2  = smemF + 9408;       // 128x36
            float* red5 = smemF + 14016;
            float* pp   = red5 + 40;
            int bb = blk;
            const float* h = P.h_dec + (size_t)bb*HDIM;
            attn_params_dev(h, P.Wwa, P.bwa, red5, pp, tid);
            float invg = expf(-pp[4]);
            fill_fb_R(sFx, sFy, pp, tid);
            for(int i=tid;i<NGRID*NGRID;i+=512){
                float a = P.bwr[i];
                #pragma unroll
                for(int s=0;s<4;s++) a += Pw[(size_t)s*BATCHN*1024 + (size_t)bb*1024 + i];
                sw[(i>>5)*36 + (i&31)] = a;
            }
            __syncthreads();
            {
                int p = tid>>2, iq = tid&3;
                float a[8];
                #pragma unroll
                for(int i=0;i<8;i++) a[i]=0.f;
                for(int j=0;j<NGRID;j++){
                    float fy = sFy[j*129 + p];
                    float4 w0 = *(const float4*)&sw[j*36 + iq*8];
                    float4 w1 = *(const float4*)&sw[j*36 + iq*8 + 4];
                    a[0]+=fy*w0.x; a[1]+=fy*w0.y; a[2]+=fy*w0.z; a[3]+=fy*w0.w;
                    a[4]+=fy*w1.x; a[5]+=fy*w1.y; a[6]+=fy*w1.z; a[7]+=fy*w1.w;
                }
                float4 o0; o0.x=a[0];o0.y=a[1];o0.z=a[2];o0.w=a[3];
                float4 o1; o1.x=a[4];o1.y=a[5];o1.z=a[6];o1.w=a[7];
                *(float4*)&tt2[p*36 + iq*8]     = o0;
                *(float4*)&tt2[p*36 + iq*8 + 4] = o1;
            }
            __syncthreads();
            {
                int q = tid&127, pg = tid>>7;
                float fxc[32];
                #pragma unroll
                for(int i=0;i<32;i++) fxc[i] = sFx[i*129 + q];
                for(int pi=0; pi<32; pi++){
                    int p = pg*32 + pi;
                    float acc = 0.f;
                    #pragma unroll
                    for(int i4=0;i4<8;i4++){
                        float4 tv = *(const float4*)&tt2[p*36 + i4*4];
                        acc += tv.x*fxc[i4*4] + tv.y*fxc[i4*4+1] + tv.z*fxc[i4*4+2] + tv.w*fxc[i4*4+3];
                    }
                    size_t off = (size_t)bb*IMGSZ + p*ABDIM + q;
                    float nv = P.rec[off] + acc*invg;
                    P.rec[off] = nv;
                    if(bb==BATCHN-1) P.s_last[p*ABDIM + q] = sigmoidf_(nv);
                }
            }
        }
        gg.sync();
    }
    // ========== final sigmoid over rec ==========
    for(size_t i = (size_t)blk*512 + tid; i < (size_t)BATCHN*IMGSZ; i += 131072)
        P.rec[i] = sigmoidf_(P.rec[i]);
}

extern "C" void kernel_launch(void* const* d_in, const int* in_sizes, int n_in,
                              void* d_out, int out_size, void* d_ws, size_t ws_size,
                              hipStream_t stream) {
    const float* x        = (const float*)d_in[0];
    const float* eps      = (const float*)d_in[1];
    const float* W_ih_enc = (const float*)d_in[2];
    const float* W_hh_enc = (const float*)d_in[3];
    const float* b_ih_enc = (const float*)d_in[4];
    const float* b_hh_enc = (const float*)d_in[5];
    const float* W_ih_dec = (const float*)d_in[6];
    const float* W_hh_dec = (const float*)d_in[7];
    const float* b_ih_dec = (const float*)d_in[8];
    const float* b_hh_dec = (const float*)d_in[9];
    const float* W_mu     = (const float*)d_in[10];
    const float* b_mu     = (const float*)d_in[11];
    const float* W_ls     = (const float*)d_in[12];
    const float* b_ls     = (const float*)d_in[13];
    const float* W_wr     = (const float*)d_in[14];
    const float* b_wr     = (const float*)d_in[15];
    const float* W_ra     = (const float*)d_in[16];
    const float* b_ra     = (const float*)d_in[17];
    const float* W_wa     = (const float*)d_in[18];
    const float* b_wa     = (const float*)d_in[19];

    float* rec = (float*)d_out;

    float* ws = (float*)d_ws;
    float* h_enc  = ws;  ws += BATCHN*HDIM;
    float* h_dec  = ws;  ws += BATCHN*HDIM;
    float* s_last = ws;  ws += IMGSZ;
    float* Pi     = ws;  ws += (size_t)5*SLAB;
    float* Ph     = ws;  ws += (size_t)2*SLAB;
    float* Ph2    = ws;  ws += (size_t)2*SLAB;

    ushort* us = (ushort*)ws;
    ushort* Wie_h = us; us += 1536*2560;
    ushort* Wie_l = us; us += 1536*2560;
    ushort* Whe_h = us; us += 1536*512;
    ushort* Whe_l = us; us += 1536*512;
    ushort* Wid_h = us; us += 1536*128;
    ushort* Wid_l = us; us += 1536*128;
    ushort* Whd_h = us; us += 1536*512;
    ushort* Whd_l = us; us += 1536*512;
    ushort* Wwr_h = us; us += 1024*512;
    ushort* Wwr_l = us; us += 1024*512;
    ushort* Eh    = us; us += BATCHN*ENCIN;
    ushort* El    = us; us += BATCHN*ENCIN;
    ushort* He_h  = us; us += BATCHN*HDIM;
    ushort* He_l  = us; us += BATCHN*HDIM;
    ushort* Hd_h  = us; us += BATCHN*HDIM;
    ushort* Hd_l  = us; us += BATCHN*HDIM;
    ushort* Zh    = us; us += BATCHN*ZDIM;
    ushort* Zl    = us; us += BATCHN*ZDIM;

    hipMemsetAsync(rec,   0, (size_t)BATCHN*IMGSZ*sizeof(float), stream);
    hipMemsetAsync(h_enc, 0, (size_t)BATCHN*HDIM*sizeof(float), stream);
    hipMemsetAsync(h_dec, 0, (size_t)BATCHN*HDIM*sizeof(float), stream);
    hipMemsetAsync(He_h,  0, (size_t)BATCHN*HDIM*sizeof(ushort)*2, stream);  // He_h+He_l contiguous
    hipMemsetAsync(Hd_h,  0, (size_t)BATCHN*HDIM*sizeof(ushort)*2, stream);  // Hd_h+Hd_l contiguous
    init_slast_k<<<IMGSZ/256,256,0,stream>>>(s_last);

    conv_w_k<<<(1536*2560/4+255)/256,256,0,stream>>>(W_ih_enc, Wie_h, Wie_l, 1536*2560/4);
    conv_w_k<<<(1536*512/4+255)/256,256,0,stream>>>(W_hh_enc, Whe_h, Whe_l, 1536*512/4);
    conv_w_k<<<(1536*128/4+255)/256,256,0,stream>>>(W_ih_dec, Wid_h, Wid_l, 1536*128/4);
    conv_w_k<<<(1536*512/4+255)/256,256,0,stream>>>(W_hh_dec, Whd_h, Whd_l, 1536*512/4);
    conv_w_k<<<(1024*512/4+255)/256,256,0,stream>>>(W_wr, Wwr_h, Wwr_l, 1024*512/4);

    MegaP mp;
    mp.x = x; mp.eps = eps;
    mp.bie = b_ih_enc; mp.bhe = b_hh_enc; mp.bid_ = b_ih_dec; mp.bhd = b_hh_dec;
    mp.Wmu = W_mu; mp.bmu = b_mu; mp.Wls = W_ls; mp.bls = b_ls;
    mp.bwr = b_wr; mp.Wra = W_ra; mp.bra = b_ra; mp.Wwa = W_wa; mp.bwa = b_wa;
    mp.rec = rec; mp.h_enc = h_enc; mp.h_dec = h_dec; mp.s_last = s_last;
    mp.Wie_h=Wie_h; mp.Wie_l=Wie_l; mp.Whe_h=Whe_h; mp.Whe_l=Whe_l;
    mp.Wid_h=Wid_h; mp.Wid_l=Wid_l; mp.Whd_h=Whd_h; mp.Whd_l=Whd_l;
    mp.Wwr_h=Wwr_h; mp.Wwr_l=Wwr_l;
    mp.Eh=Eh; mp.El=El; mp.He_h=He_h; mp.He_l=He_l; mp.Hd_h=Hd_h; mp.Hd_l=Hd_l;
    mp.Zh=Zh; mp.Zl=Zl;
    mp.Pi=Pi; mp.Ph=Ph; mp.Ph2=Ph2;

    void* kargs[] = { (void*)&mp };
    hipLaunchCooperativeKernel(mega_k, dim3(256), dim3(512), kargs, 0u, stream);
}

// Round 7
// 2145.636 us; speedup vs baseline: 2.4595x; 2.4595x over previous
//
#include <hip/hip_runtime.h>
#include <math.h>

#define BATCHN 256
#define HDIM 512
#define ZDIM 128
#define NGRID 32
#define ABDIM 128
#define IMGSZ 16384   // 128*128
#define ENCIN 2560
#define G3 1536
#define SLAB (BATCHN*G3)

typedef __attribute__((ext_vector_type(8))) short short8;
typedef __attribute__((ext_vector_type(4))) float f32x4;

__device__ __forceinline__ float sigmoidf_(float x){ return 1.0f/(1.0f+expf(-x)); }

__device__ __forceinline__ ushort f2bf_rne(float f){
    union{float f; uint u;} x; x.f=f;
    uint r = (x.u + 0x7FFFu + ((x.u>>16)&1u)) >> 16;
    return (ushort)r;
}
__device__ __forceinline__ float bf2f(ushort h){
    union{uint u; float f;} y; y.u = ((uint)h)<<16;
    return y.f;
}

__global__ void init_slast_k(float* __restrict__ s_last){
    int i = blockIdx.x*256 + threadIdx.x;
    s_last[i] = 0.5f;   // sigmoid(0)
}

// convert f32 weights -> bf16 hi/lo arrays (vector-4)
__global__ void conv_w_k(const float* __restrict__ W, ushort* __restrict__ Wh,
                         ushort* __restrict__ Wl, int n4){
    int i = blockIdx.x*256 + threadIdx.x;
    if(i>=n4) return;
    float4 v = ((const float4*)W)[i];
    float f[4] = {v.x, v.y, v.z, v.w};
    ushort h[4], l[4];
    #pragma unroll
    for(int j=0;j<4;j++){
        h[j] = f2bf_rne(f[j]);
        l[j] = f2bf_rne(f[j] - bf2f(h[j]));
    }
    ushort4 hv; hv.x=h[0]; hv.y=h[1]; hv.z=h[2]; hv.w=h[3];
    ushort4 lv; lv.x=l[0]; lv.y=l[1]; lv.z=l[2]; lv.w=l[3];
    ((ushort4*)Wh)[i] = hv;
    ((ushort4*)Wl)[i] = lv;
}

// ---- attention params with NT=512 threads ----
__device__ __forceinline__ void attn_params_dev512(const float* __restrict__ h,
        const float* __restrict__ W, const float* __restrict__ bvec,
        float* red5, float* pp, int tid){
    float accp[5];
    #pragma unroll
    for(int i=0;i<5;i++) accp[i]=0.f;
    for(int k=tid;k<HDIM;k+=512){
        float hv = h[k];
        #pragma unroll
        for(int i=0;i<5;i++) accp[i] += hv*W[i*HDIM+k];
    }
    int wv = tid>>6;
    #pragma unroll
    for(int i=0;i<5;i++){
        float a = accp[i];
        #pragma unroll
        for(int o=32;o>0;o>>=1) a += __shfl_down(a,o);
        if((tid&63)==0) red5[i*8+wv]=a;
    }
    __syncthreads();
    if(tid<5){
        float s = bvec[tid];
        #pragma unroll
        for(int w2=0;w2<8;w2++) s += red5[tid*8+w2];
        pp[tid]=s;
    }
    __syncthreads();
}

// transposed fill: fxT[pix][j], fyT[pix][j]; NT=512
__device__ __forceinline__ void fill_fb_T(float* fxT, float* fyT, const float* pp, int tid){
    float gx = 64.5f*(pp[0]+1.0f);
    float gy = 64.5f*(pp[1]+1.0f);
    float tss = 2.0f*expf(pp[2]);
    float delta = (127.0f/31.0f)*expf(pp[3]);
    int rr = tid>>3;
    int q  = tid&7;
    int j  = rr&31;
    bool isY = rr>=32;
    float mu = (isY?gy:gx) + ((float)j-15.5f)*delta;
    float v[16]; float s=0.f;
    #pragma unroll
    for(int i=0;i<16;i++){
        float d = (float)(q*16+i)-mu;
        float e = expf(-d*d/tss);
        v[i]=e; s+=e;
    }
    s += __shfl_xor(s,1); s += __shfl_xor(s,2); s += __shfl_xor(s,4);
    float inv = 1.0f/fmaxf(s,1e-8f);
    float* dst = isY? fyT : fxT;
    #pragma unroll
    for(int i=0;i<16;i++) dst[(q*16+i)*32 + j] = v[i]*inv;
    __syncthreads();
}

// row-major fill: fx[32][129], fy[32][129]; NT=512
__device__ __forceinline__ void fill_fb_R(float (*fx)[ABDIM+1], float (*fy)[ABDIM+1], const float* pp, int tid){
    float gx = 64.5f*(pp[0]+1.0f);
    float gy = 64.5f*(pp[1]+1.0f);
    float tss = 2.0f*expf(pp[2]);
    float delta = (127.0f/31.0f)*expf(pp[3]);
    int rr = tid>>3;
    int q  = tid&7;
    int j  = rr&31;
    bool isY = rr>=32;
    float mu = (isY?gy:gx) + ((float)j-15.5f)*delta;
    float v[16]; float s=0.f;
    #pragma unroll
    for(int i=0;i<16;i++){
        float d = (float)(q*16+i)-mu;
        float e = expf(-d*d/tss);
        v[i]=e; s+=e;
    }
    s += __shfl_xor(s,1); s += __shfl_xor(s,2); s += __shfl_xor(s,4);
    float inv = 1.0f/fmaxf(s,1e-8f);
    float* rowp = isY? &fy[j][0] : &fx[j][0];
    #pragma unroll
    for(int i=0;i<16;i++) rowp[q*16+i] = v[i]*inv;
    __syncthreads();
}

// per-batch fused read attention; 512 threads; writes enc_in as bf16 hi/lo
__global__ __launch_bounds__(512) void read_attn_k(const float* __restrict__ xf, const float* __restrict__ s_last,
        const float* __restrict__ hdec, const ushort* __restrict__ Hd_h, const ushort* __restrict__ Hd_l,
        const float* __restrict__ W_ra, const float* __restrict__ b_ra,
        ushort* __restrict__ Eh, ushort* __restrict__ El){
    __shared__ float smem[4096 + 8256 + 48];
    float* sFxT = smem;
    float* sFyT = smem + 4096;
    float* tmp  = smem + 4096;            // aliases sFyT (barrier-separated)
    float* red5 = smem + 4096 + 8256;
    float* pp   = red5 + 40;
    int bb = blockIdx.x; int tid = threadIdx.x;
    const float* h = hdec + bb*HDIM;
    attn_params_dev512(h, W_ra, b_ra, red5, pp, tid);
    float gamma = expf(pp[4]);
    fill_fb_T(sFxT, sFyT, pp, tid);

    const float* img = xf + (size_t)bb*IMGSZ;
    int c = tid & 127;
    int jg = tid >> 7;
    float acc0[8], accS[8];
    #pragma unroll
    for(int i=0;i<8;i++){ acc0[i]=0.f; accS[i]=0.f; }
    for(int k=0;k<ABDIM;k++){
        float s  = img[k*ABDIM + c];
        float sl = s_last[k*ABDIM + c];
        float4 f0 = *(const float4*)&sFyT[k*32 + jg*8];
        float4 f1 = *(const float4*)&sFyT[k*32 + jg*8 + 4];
        acc0[0]+=f0.x*s;  acc0[1]+=f0.y*s;  acc0[2]+=f0.z*s;  acc0[3]+=f0.w*s;
        acc0[4]+=f1.x*s;  acc0[5]+=f1.y*s;  acc0[6]+=f1.z*s;  acc0[7]+=f1.w*s;
        accS[0]+=f0.x*sl; accS[1]+=f0.y*sl; accS[2]+=f0.z*sl; accS[3]+=f0.w*sl;
        accS[4]+=f1.x*sl; accS[5]+=f1.y*sl; accS[6]+=f1.z*sl; accS[7]+=f1.w*sl;
    }
    __syncthreads();
    #pragma unroll
    for(int i=0;i<8;i++){
        int j = jg*8+i;
        tmp[0*32*129 + j*129 + c] = acc0[i];
        tmp[1*32*129 + j*129 + c] = acc0[i] - accS[i];
    }
    __syncthreads();
    {
        int i4 = tid & 7;
        int j  = (tid>>3) & 31;
        int p  = tid >> 8;
        float a0=0.f,a1=0.f,a2=0.f,a3=0.f;
        for(int cc=0; cc<ABDIM; cc++){
            float tv = tmp[p*32*129 + j*129 + cc];
            float4 fx = *(const float4*)&sFxT[cc*32 + i4*4];
            a0 += tv*fx.x; a1 += tv*fx.y; a2 += tv*fx.z; a3 += tv*fx.w;
        }
        float ov[4] = {gamma*a0, gamma*a1, gamma*a2, gamma*a3};
        ushort4 oh, ol; ushort hq;
        hq=f2bf_rne(ov[0]); oh.x=hq; ol.x=f2bf_rne(ov[0]-bf2f(hq));
        hq=f2bf_rne(ov[1]); oh.y=hq; ol.y=f2bf_rne(ov[1]-bf2f(hq));
        hq=f2bf_rne(ov[2]); oh.z=hq; ol.z=f2bf_rne(ov[2]-bf2f(hq));
        hq=f2bf_rne(ov[3]); oh.w=hq; ol.w=f2bf_rne(ov[3]-bf2f(hq));
        size_t off = (size_t)bb*ENCIN + p*1024 + j*NGRID + i4*4;
        *(ushort4*)(Eh + off) = oh;
        *(ushort4*)(El + off) = ol;
    }
    {
        int i = tid;
        Eh[(size_t)bb*ENCIN + 2048 + i] = Hd_h[(size_t)bb*HDIM + i];
        El[(size_t)bb*ENCIN + 2048 + i] = Hd_l[(size_t)bb*HDIM + i];
    }
}

// ---- one MFMA GEMM tile (split-bf16, 3 products), 64x64, 256thr, BK=64 ----
__device__ void gemm_one(const ushort* __restrict__ Agh, const ushort* __restrict__ Agl,
        const ushort* __restrict__ Wh, const ushort* __restrict__ Wl,
        int K, int k0, int kiters, int row0, int col0, int Nn, float* __restrict__ Out,
        ushort* AH, ushort* AL, ushort* BH, ushort* BL, int tid){
    int lane = tid&63, w = tid>>6;
    int m0 = (w>>1)*32, n0 = (w&1)*32;
    int fr = lane&15, kq = (lane>>4)*8;
    int sr = tid>>2, sq = (tid&3)*16;
    f32x4 acc[2][2];
    #pragma unroll
    for(int i=0;i<2;i++)
        #pragma unroll
        for(int j=0;j<2;j++) acc[i][j]=(f32x4){0.f,0.f,0.f,0.f};
    for(int it=0; it<kiters; ++it){
        int kb = k0 + it*64;
        size_t aoff = (size_t)(row0+sr)*K + kb + sq;
        size_t boff = (size_t)(col0+sr)*K + kb + sq;
        uint4 ah0 = *(const uint4*)(Agh + aoff);
        uint4 ah1 = *(const uint4*)(Agh + aoff + 8);
        uint4 al0 = *(const uint4*)(Agl + aoff);
        uint4 al1 = *(const uint4*)(Agl + aoff + 8);
        uint4 bh0 = *(const uint4*)(Wh + boff);
        uint4 bh1 = *(const uint4*)(Wh + boff + 8);
        uint4 bl0 = *(const uint4*)(Wl + boff);
        uint4 bl1 = *(const uint4*)(Wl + boff + 8);
        __syncthreads();
        *(uint4*)&AH[sr*72 + sq]     = ah0;
        *(uint4*)&AH[sr*72 + sq + 8] = ah1;
        *(uint4*)&AL[sr*72 + sq]     = al0;
        *(uint4*)&AL[sr*72 + sq + 8] = al1;
        *(uint4*)&BH[sr*72 + sq]     = bh0;
        *(uint4*)&BH[sr*72 + sq + 8] = bh1;
        *(uint4*)&BL[sr*72 + sq]     = bl0;
        *(uint4*)&BL[sr*72 + sq + 8] = bl1;
        __syncthreads();
        #pragma unroll
        for(int ks=0; ks<2; ks++){
            int kk = ks*32 + kq;
            short8 a_h[2], a_l[2], b_h[2], b_l[2];
            #pragma unroll
            for(int mf=0;mf<2;mf++){
                a_h[mf] = *(short8*)&AH[(m0+mf*16+fr)*72 + kk];
                a_l[mf] = *(short8*)&AL[(m0+mf*16+fr)*72 + kk];
            }
            #pragma unroll
            for(int nf=0;nf<2;nf++){
                b_h[nf] = *(short8*)&BH[(n0+nf*16+fr)*72 + kk];
                b_l[nf] = *(short8*)&BL[(n0+nf*16+fr)*72 + kk];
            }
            #pragma unroll
            for(int mf=0;mf<2;mf++)
                #pragma unroll
                for(int nf=0;nf<2;nf++){
                    acc[mf][nf] = __builtin_amdgcn_mfma_f32_16x16x32_bf16(a_h[mf], b_h[nf], acc[mf][nf], 0,0,0);
                    acc[mf][nf] = __builtin_amdgcn_mfma_f32_16x16x32_bf16(a_h[mf], b_l[nf], acc[mf][nf], 0,0,0);
                    acc[mf][nf] = __builtin_amdgcn_mfma_f32_16x16x32_bf16(a_l[mf], b_h[nf], acc[mf][nf], 0,0,0);
                }
        }
    }
    int crow = (lane>>4)*4, ccol = lane&15;
    #pragma unroll
    for(int mf=0;mf<2;mf++)
        #pragma unroll
        for(int nf=0;nf<2;nf++)
            #pragma unroll
            for(int r=0;r<4;r++)
                Out[(size_t)(row0+m0+mf*16+crow+r)*Nn + col0+n0+nf*16+ccol] = acc[mf][nf][r];
}

// job pool: enc-i (192 jobs, splitk2) + enc-h (96) + dec-h (96) = 384 blocks
__global__ __launch_bounds__(256) void gemm3_k(
        const ushort* __restrict__ Eh, const ushort* __restrict__ El,
        const ushort* __restrict__ Wie_h, const ushort* __restrict__ Wie_l,
        const ushort* __restrict__ He_h, const ushort* __restrict__ He_l,
        const ushort* __restrict__ Whe_h, const ushort* __restrict__ Whe_l,
        const ushort* __restrict__ Hd_h, const ushort* __restrict__ Hd_l,
        const ushort* __restrict__ Whd_h, const ushort* __restrict__ Whd_l,
        float* __restrict__ Pi, float* __restrict__ Ph, float* __restrict__ Ph2){
    __shared__ ushort AH[64*72], AL[64*72], BH[64*72], BL[64*72];
    int job = blockIdx.x, tid = threadIdx.x;
    const ushort *Ah_,*Al_,*Wh_,*Wl_; int K_,k0_,ki_,r0_,c0_; float* Out_;
    if(job < 192){
        int tile = job % 96, s = job / 96;
        Ah_=Eh; Al_=El; Wh_=Wie_h; Wl_=Wie_l;
        K_=ENCIN; k0_=s*1280; ki_=20;
        r0_=(tile/24)*64; c0_=(tile%24)*64;
        Out_ = Pi + (size_t)s*SLAB;
    } else if(job < 288){
        int tile = job - 192;
        Ah_=He_h; Al_=He_l; Wh_=Whe_h; Wl_=Whe_l;
        K_=HDIM; k0_=0; ki_=8;
        r0_=(tile/24)*64; c0_=(tile%24)*64;
        Out_ = Ph;
    } else {
        int tile = job - 288;
        Ah_=Hd_h; Al_=Hd_l; Wh_=Whd_h; Wl_=Whd_l;
        K_=HDIM; k0_=0; ki_=8;
        r0_=(tile/24)*64; c0_=(tile%24)*64;
        Out_ = Ph2;
    }
    gemm_one(Ah_, Al_, Wh_, Wl_, K_, k0_, ki_, r0_, c0_, G3, Out_, AH, AL, BH, BL, tid);
}

// write GEMM: grid (16 cols, 4 rows, 4 splits), 64x64 tiles, K=512
__global__ __launch_bounds__(256) void gemm_wr_k(
        const ushort* __restrict__ Hd_h, const ushort* __restrict__ Hd_l,
        const ushort* __restrict__ Wwr_h, const ushort* __restrict__ Wwr_l,
        float* __restrict__ Pw){
    __shared__ ushort AH[64*72], AL[64*72], BH[64*72], BL[64*72];
    int tid = threadIdx.x;
    int r0 = blockIdx.y*64, c0 = blockIdx.x*64, s = blockIdx.z;
    gemm_one(Hd_h, Hd_l, Wwr_h, Wwr_l, HDIM, s*128, 2, r0, c0, 1024,
             Pw + (size_t)s*BATCHN*1024, AH, AL, BH, BL, tid);
}

// encoder combine (2 Pi slabs + 1 Ph) + z sample + dec-i GEMV (K=128, f32)
__global__ __launch_bounds__(512) void combine_z_deci_k(const float* __restrict__ Pi, const float* __restrict__ Ph,
        const float* __restrict__ bi, const float* __restrict__ bh,
        float* __restrict__ h, ushort* __restrict__ Hh, ushort* __restrict__ Hl,
        const float* __restrict__ Wmu, const float* __restrict__ bmu,
        const float* __restrict__ Wls, const float* __restrict__ bls,
        const float* __restrict__ eps_t, const float* __restrict__ Wid,
        float* __restrict__ gi_dec){
    __shared__ float hs[HDIM];
    __shared__ float zs[ZDIM];
    int bb = blockIdx.x, tid = threadIdx.x;
    int j = tid;
    float gi_r=bi[j], gi_z=bi[512+j], gi_n=bi[1024+j];
    float gh_r=bh[j], gh_z=bh[512+j], gh_n=bh[1024+j];
    #pragma unroll
    for(int s=0;s<2;s++){
        size_t base = (size_t)s*SLAB + (size_t)bb*G3 + j;
        gi_r += Pi[base]; gi_z += Pi[base+512]; gi_n += Pi[base+1024];
    }
    {
        size_t base = (size_t)bb*G3 + j;
        gh_r += Ph[base]; gh_z += Ph[base+512]; gh_n += Ph[base+1024];
    }
    float r = sigmoidf_(gi_r + gh_r);
    float z = sigmoidf_(gi_z + gh_z);
    float n = tanhf(gi_n + r*gh_n);
    size_t hoff = (size_t)bb*HDIM + j;
    float hn = (1.f - z)*n + z*h[hoff];
    h[hoff] = hn; hs[j] = hn;
    ushort hh = f2bf_rne(hn);
    Hh[hoff] = hh; Hl[hoff] = f2bf_rne(hn - bf2f(hh));
    __syncthreads();
    // z sample: 4 lanes per output
    {
        int jo = tid>>2, l4 = tid&3;
        float am=0.f, al_=0.f;
        for(int k=l4;k<HDIM;k+=4){
            float hv = hs[k];
            am  += hv*Wmu[(size_t)jo*HDIM+k];
            al_ += hv*Wls[(size_t)jo*HDIM+k];
        }
        am  += __shfl_xor(am,1);  am  += __shfl_xor(am,2);
        al_ += __shfl_xor(al_,1); al_ += __shfl_xor(al_,2);
        if(l4==0){
            float mu = am + bmu[jo];
            float sg = expf(al_ + bls[jo]);
            zs[jo] = mu + eps_t[(size_t)bb*ZDIM + jo]*sg;
        }
    }
    __syncthreads();
    // dec-i GEMV: gi_dec[bb,n] = sum_k zs[k]*Wid[n,k], n = tid, tid+512, tid+1024
    #pragma unroll
    for(int rep=0; rep<3; rep++){
        int nn = tid + rep*512;
        const float4* wr = (const float4*)(Wid + (size_t)nn*ZDIM);
        float a = 0.f;
        #pragma unroll
        for(int k4=0;k4<32;k4++){
            float4 wv = wr[k4];
            a += zs[k4*4]*wv.x + zs[k4*4+1]*wv.y + zs[k4*4+2]*wv.z + zs[k4*4+3]*wv.w;
        }
        gi_dec[(size_t)bb*G3 + nn] = a;
    }
}

// decoder combine: gi_dec (full) + Ph2 (1 slab) -> h_dec + mirrors
__global__ void combine_dec_k(const float* __restrict__ gi_dec, const float* __restrict__ Ph2,
        const float* __restrict__ bi, const float* __restrict__ bh,
        float* __restrict__ h, ushort* __restrict__ Hh, ushort* __restrict__ Hl){
    int idx = blockIdx.x*256 + threadIdx.x;
    int bb = idx >> 9, j = idx & 511;
    size_t base = (size_t)bb*G3 + j;
    float gi_r = gi_dec[base]      + bi[j];
    float gi_z = gi_dec[base+512]  + bi[512+j];
    float gi_n = gi_dec[base+1024] + bi[1024+j];
    float gh_r = Ph2[base]      + bh[j];
    float gh_z = Ph2[base+512]  + bh[512+j];
    float gh_n = Ph2[base+1024] + bh[1024+j];
    float r = sigmoidf_(gi_r + gh_r);
    float z = sigmoidf_(gi_z + gh_z);
    float n = tanhf(gi_n + r*gh_n);
    float hn = (1.f - z)*n + z*h[idx];
    h[idx] = hn;
    ushort hh = f2bf_rne(hn);
    Hh[idx] = hh; Hl[idx] = f2bf_rne(hn - bf2f(hh));
}

// write path: params+filterbank+reduce(Pw,4 slabs)+apply; refresh s_last; 512 threads
__global__ __launch_bounds__(512) void write_apply_k(const float* __restrict__ Pw, const float* __restrict__ b_wr,
        const float* __restrict__ hdec, const float* __restrict__ W_wa, const float* __restrict__ b_wa,
        float* __restrict__ rec, float* __restrict__ s_last){
    __shared__ float sFy[NGRID][ABDIM+1];
    __shared__ float sFx[NGRID][ABDIM+1];
    __shared__ float sw[NGRID][36];
    __shared__ float t[ABDIM][36];
    __shared__ float red5[40];
    __shared__ float pp[8];
    int bb = blockIdx.x, tid = threadIdx.x;
    const float* h = hdec + bb*HDIM;
    attn_params_dev512(h, W_wa, b_wa, red5, pp, tid);
    float invg = expf(-pp[4]);
    fill_fb_R(sFx, sFy, pp, tid);
    for(int i=tid;i<NGRID*NGRID;i+=512){
        float a = b_wr[i];
        #pragma unroll
        for(int s=0;s<4;s++) a += Pw[((size_t)s*BATCHN + bb)*1024 + i];
        sw[i>>5][i&31] = a;
    }
    __syncthreads();
    {
        int p = tid>>2, iq = tid&3;
        float a[8];
        #pragma unroll
        for(int i=0;i<8;i++) a[i]=0.f;
        for(int j=0;j<NGRID;j++){
            float fy = sFy[j][p];
            float4 w0 = *(const float4*)&sw[j][iq*8];
            float4 w1 = *(const float4*)&sw[j][iq*8+4];
            a[0]+=fy*w0.x; a[1]+=fy*w0.y; a[2]+=fy*w0.z; a[3]+=fy*w0.w;
            a[4]+=fy*w1.x; a[5]+=fy*w1.y; a[6]+=fy*w1.z; a[7]+=fy*w1.w;
        }
        float4 o0; o0.x=a[0];o0.y=a[1];o0.z=a[2];o0.w=a[3];
        float4 o1; o1.x=a[4];o1.y=a[5];o1.z=a[6];o1.w=a[7];
        *(float4*)&t[p][iq*8]   = o0;
        *(float4*)&t[p][iq*8+4] = o1;
    }
    __syncthreads();
    {
        int q = tid&127, pg = tid>>7;
        float fxc[32];
        #pragma unroll
        for(int i=0;i<32;i++) fxc[i] = sFx[i][q];
        for(int pi=0; pi<32; pi++){
            int p = pg*32 + pi;
            float acc = 0.f;
            #pragma unroll
            for(int i4=0;i4<8;i4++){
                float4 tv = *(const float4*)&t[p][i4*4];
                acc += tv.x*fxc[i4*4] + tv.y*fxc[i4*4+1] + tv.z*fxc[i4*4+2] + tv.w*fxc[i4*4+3];
            }
            size_t off = (size_t)bb*IMGSZ + p*ABDIM + q;
            float nv = rec[off] + acc*invg;
            rec[off] = nv;
            if(bb==BATCHN-1) s_last[p*ABDIM + q] = sigmoidf_(nv);
        }
    }
}

__global__ void sigmoid_all_k(float* __restrict__ rec){
    int i = blockIdx.x*256 + threadIdx.x;
    rec[i] = sigmoidf_(rec[i]);
}

extern "C" void kernel_launch(void* const* d_in, const int* in_sizes, int n_in,
                              void* d_out, int out_size, void* d_ws, size_t ws_size,
                              hipStream_t stream) {
    const float* x        = (const float*)d_in[0];
    const float* eps      = (const float*)d_in[1];
    const float* W_ih_enc = (const float*)d_in[2];
    const float* W_hh_enc = (const float*)d_in[3];
    const float* b_ih_enc = (const float*)d_in[4];
    const float* b_hh_enc = (const float*)d_in[5];
    const float* W_ih_dec = (const float*)d_in[6];
    const float* W_hh_dec = (const float*)d_in[7];
    const float* b_ih_dec = (const float*)d_in[8];
    const float* b_hh_dec = (const float*)d_in[9];
    const float* W_mu     = (const float*)d_in[10];
    const float* b_mu     = (const float*)d_in[11];
    const float* W_ls     = (const float*)d_in[12];
    const float* b_ls     = (const float*)d_in[13];
    const float* W_wr     = (const float*)d_in[14];
    const float* b_wr     = (const float*)d_in[15];
    const float* W_ra     = (const float*)d_in[16];
    const float* b_ra     = (const float*)d_in[17];
    const float* W_wa     = (const float*)d_in[18];
    const float* b_wa     = (const float*)d_in[19];

    float* rec = (float*)d_out;

    float* ws = (float*)d_ws;
    float* h_enc  = ws;  ws += BATCHN*HDIM;
    float* h_dec  = ws;  ws += BATCHN*HDIM;
    float* s_last = ws;  ws += IMGSZ;
    float* Pi     = ws;  ws += (size_t)2*SLAB;
    float* Ph     = ws;  ws += (size_t)SLAB;
    float* Ph2    = ws;  ws += (size_t)SLAB;
    float* gi_dec = ws;  ws += (size_t)SLAB;
    float* Pw     = ws;  ws += (size_t)4*BATCHN*1024;

    ushort* us = (ushort*)ws;
    ushort* Wie_h = us; us += 1536*2560;
    ushort* Wie_l = us; us += 1536*2560;
    ushort* Whe_h = us; us += 1536*512;
    ushort* Whe_l = us; us += 1536*512;
    ushort* Whd_h = us; us += 1536*512;
    ushort* Whd_l = us; us += 1536*512;
    ushort* Wwr_h = us; us += 1024*512;
    ushort* Wwr_l = us; us += 1024*512;
    ushort* Eh    = us; us += BATCHN*ENCIN;
    ushort* El    = us; us += BATCHN*ENCIN;
    ushort* He_h  = us; us += BATCHN*HDIM;
    ushort* He_l  = us; us += BATCHN*HDIM;
    ushort* Hd_h  = us; us += BATCHN*HDIM;
    ushort* Hd_l  = us; us += BATCHN*HDIM;

    hipMemsetAsync(rec,   0, (size_t)BATCHN*IMGSZ*sizeof(float), stream);
    hipMemsetAsync(h_enc, 0, (size_t)BATCHN*HDIM*sizeof(float), stream);
    hipMemsetAsync(h_dec, 0, (size_t)BATCHN*HDIM*sizeof(float), stream);
    hipMemsetAsync(He_h,  0, (size_t)BATCHN*HDIM*sizeof(ushort)*2, stream);  // He_h+He_l contiguous
    hipMemsetAsync(Hd_h,  0, (size_t)BATCHN*HDIM*sizeof(ushort)*2, stream);  // Hd_h+Hd_l contiguous
    init_slast_k<<<IMGSZ/256,256,0,stream>>>(s_last);

    conv_w_k<<<(1536*2560/4+255)/256,256,0,stream>>>(W_ih_enc, Wie_h, Wie_l, 1536*2560/4);
    conv_w_k<<<(1536*512/4+255)/256,256,0,stream>>>(W_hh_enc, Whe_h, Whe_l, 1536*512/4);
    conv_w_k<<<(1536*512/4+255)/256,256,0,stream>>>(W_hh_dec, Whd_h, Whd_l, 1536*512/4);
    conv_w_k<<<(1024*512/4+255)/256,256,0,stream>>>(W_wr, Wwr_h, Wwr_l, 1024*512/4);

    for(int t=0;t<16;t++){
        read_attn_k<<<BATCHN,512,0,stream>>>(x, s_last, h_dec, Hd_h, Hd_l, W_ra, b_ra, Eh, El);
        gemm3_k<<<384,256,0,stream>>>(Eh, El, Wie_h, Wie_l, He_h, He_l, Whe_h, Whe_l,
                                      Hd_h, Hd_l, Whd_h, Whd_l, Pi, Ph, Ph2);
        combine_z_deci_k<<<BATCHN,512,0,stream>>>(Pi, Ph, b_ih_enc, b_hh_enc,
            h_enc, He_h, He_l, W_mu, b_mu, W_ls, b_ls, eps + (size_t)t*BATCHN*ZDIM,
            W_ih_dec, gi_dec);
        combine_dec_k<<<BATCHN*HDIM/256,256,0,stream>>>(gi_dec, Ph2, b_ih_dec, b_hh_dec,
            h_dec, Hd_h, Hd_l);
        gemm_wr_k<<<dim3(16,4,4),256,0,stream>>>(Hd_h, Hd_l, Wwr_h, Wwr_l, Pw);
        write_apply_k<<<BATCHN,512,0,stream>>>(Pw, b_wr, h_dec, W_wa, b_wa, rec, s_last);
    }
    sigmoid_all_k<<<BATCHN*IMGSZ/256,256,0,stream>>>(rec);
}

// Round 8
// 1621.017 us; speedup vs baseline: 3.2554x; 1.3236x over previous
//
#include <hip/hip_runtime.h>
#include <math.h>

#define BATCHN 256
#define HDIM 512
#define ZDIM 128
#define NGRID 32
#define ABDIM 128
#define IMGSZ 16384   // 128*128
#define ENCIN 2560
#define G3 1536
#define SLAB (BATCHN*G3)

typedef __attribute__((ext_vector_type(8))) short short8;
typedef __attribute__((ext_vector_type(4))) float f32x4;

__device__ __forceinline__ float sigmoidf_(float x){ return 1.0f/(1.0f+expf(-x)); }

__device__ __forceinline__ ushort f2bf_rne(float f){
    union{float f; uint u;} x; x.f=f;
    uint r = (x.u + 0x7FFFu + ((x.u>>16)&1u)) >> 16;
    return (ushort)r;
}
__device__ __forceinline__ float bf2f(ushort h){
    union{uint u; float f;} y; y.u = ((uint)h)<<16;
    return y.f;
}

__global__ void init_slast_k(float* __restrict__ s_last){
    int i = blockIdx.x*256 + threadIdx.x;
    s_last[i] = 0.5f;   // sigmoid(0)
}

// convert f32 weights -> bf16 hi/lo arrays (vector-4)
__global__ void conv_w_k(const float* __restrict__ W, ushort* __restrict__ Wh,
                         ushort* __restrict__ Wl, int n4){
    int i = blockIdx.x*256 + threadIdx.x;
    if(i>=n4) return;
    float4 v = ((const float4*)W)[i];
    float f[4] = {v.x, v.y, v.z, v.w};
    ushort h[4], l[4];
    #pragma unroll
    for(int j=0;j<4;j++){
        h[j] = f2bf_rne(f[j]);
        l[j] = f2bf_rne(f[j] - bf2f(h[j]));
    }
    ushort4 hv; hv.x=h[0]; hv.y=h[1]; hv.z=h[2]; hv.w=h[3];
    ushort4 lv; lv.x=l[0]; lv.y=l[1]; lv.z=l[2]; lv.w=l[3];
    ((ushort4*)Wh)[i] = hv;
    ((ushort4*)Wl)[i] = lv;
}

// ---- attention params with NT=512 threads ----
__device__ __forceinline__ void attn_params_dev512(const float* __restrict__ h,
        const float* __restrict__ W, const float* __restrict__ bvec,
        float* red5, float* pp, int tid){
    float accp[5];
    #pragma unroll
    for(int i=0;i<5;i++) accp[i]=0.f;
    for(int k=tid;k<HDIM;k+=512){
        float hv = h[k];
        #pragma unroll
        for(int i=0;i<5;i++) accp[i] += hv*W[i*HDIM+k];
    }
    int wv = tid>>6;
    #pragma unroll
    for(int i=0;i<5;i++){
        float a = accp[i];
        #pragma unroll
        for(int o=32;o>0;o>>=1) a += __shfl_down(a,o);
        if((tid&63)==0) red5[i*8+wv]=a;
    }
    __syncthreads();
    if(tid<5){
        float s = bvec[tid];
        #pragma unroll
        for(int w2=0;w2<8;w2++) s += red5[tid*8+w2];
        pp[tid]=s;
    }
    __syncthreads();
}

// transposed fill: fxT[pix][j], fyT[pix][j]; NT=512
__device__ __forceinline__ void fill_fb_T(float* fxT, float* fyT, const float* pp, int tid){
    float gx = 64.5f*(pp[0]+1.0f);
    float gy = 64.5f*(pp[1]+1.0f);
    float tss = 2.0f*expf(pp[2]);
    float delta = (127.0f/31.0f)*expf(pp[3]);
    int rr = tid>>3;
    int q  = tid&7;
    int j  = rr&31;
    bool isY = rr>=32;
    float mu = (isY?gy:gx) + ((float)j-15.5f)*delta;
    float v[16]; float s=0.f;
    #pragma unroll
    for(int i=0;i<16;i++){
        float d = (float)(q*16+i)-mu;
        float e = expf(-d*d/tss);
        v[i]=e; s+=e;
    }
    s += __shfl_xor(s,1); s += __shfl_xor(s,2); s += __shfl_xor(s,4);
    float inv = 1.0f/fmaxf(s,1e-8f);
    float* dst = isY? fyT : fxT;
    #pragma unroll
    for(int i=0;i<16;i++) dst[(q*16+i)*32 + j] = v[i]*inv;
    __syncthreads();
}

// row-major fill: fx[32][129], fy[32][129]; NT=512
__device__ __forceinline__ void fill_fb_R(float (*fx)[ABDIM+1], float (*fy)[ABDIM+1], const float* pp, int tid){
    float gx = 64.5f*(pp[0]+1.0f);
    float gy = 64.5f*(pp[1]+1.0f);
    float tss = 2.0f*expf(pp[2]);
    float delta = (127.0f/31.0f)*expf(pp[3]);
    int rr = tid>>3;
    int q  = tid&7;
    int j  = rr&31;
    bool isY = rr>=32;
    float mu = (isY?gy:gx) + ((float)j-15.5f)*delta;
    float v[16]; float s=0.f;
    #pragma unroll
    for(int i=0;i<16;i++){
        float d = (float)(q*16+i)-mu;
        float e = expf(-d*d/tss);
        v[i]=e; s+=e;
    }
    s += __shfl_xor(s,1); s += __shfl_xor(s,2); s += __shfl_xor(s,4);
    float inv = 1.0f/fmaxf(s,1e-8f);
    float* rowp = isY? &fy[j][0] : &fx[j][0];
    #pragma unroll
    for(int i=0;i<16;i++) rowp[q*16+i] = v[i]*inv;
    __syncthreads();
}

// per-batch fused read attention; 512 threads; writes enc_in as bf16 hi/lo
__global__ __launch_bounds__(512) void read_attn_k(const float* __restrict__ xf, const float* __restrict__ s_last,
        const float* __restrict__ hdec, const ushort* __restrict__ Hd_h, const ushort* __restrict__ Hd_l,
        const float* __restrict__ W_ra, const float* __restrict__ b_ra,
        ushort* __restrict__ Eh, ushort* __restrict__ El){
    __shared__ float smem[4096 + 8256 + 48];
    float* sFxT = smem;
    float* sFyT = smem + 4096;
    float* tmp  = smem + 4096;            // aliases sFyT (barrier-separated)
    float* red5 = smem + 4096 + 8256;
    float* pp   = red5 + 40;
    int bb = blockIdx.x; int tid = threadIdx.x;
    const float* h = hdec + bb*HDIM;
    attn_params_dev512(h, W_ra, b_ra, red5, pp, tid);
    float gamma = expf(pp[4]);
    fill_fb_T(sFxT, sFyT, pp, tid);

    const float* img = xf + (size_t)bb*IMGSZ;
    int c = tid & 127;
    int jg = tid >> 7;
    float acc0[8], accS[8];
    #pragma unroll
    for(int i=0;i<8;i++){ acc0[i]=0.f; accS[i]=0.f; }
    for(int k=0;k<ABDIM;k++){
        float s  = img[k*ABDIM + c];
        float sl = s_last[k*ABDIM + c];
        float4 f0 = *(const float4*)&sFyT[k*32 + jg*8];
        float4 f1 = *(const float4*)&sFyT[k*32 + jg*8 + 4];
        acc0[0]+=f0.x*s;  acc0[1]+=f0.y*s;  acc0[2]+=f0.z*s;  acc0[3]+=f0.w*s;
        acc0[4]+=f1.x*s;  acc0[5]+=f1.y*s;  acc0[6]+=f1.z*s;  acc0[7]+=f1.w*s;
        accS[0]+=f0.x*sl; accS[1]+=f0.y*sl; accS[2]+=f0.z*sl; accS[3]+=f0.w*sl;
        accS[4]+=f1.x*sl; accS[5]+=f1.y*sl; accS[6]+=f1.z*sl; accS[7]+=f1.w*sl;
    }
    __syncthreads();
    #pragma unroll
    for(int i=0;i<8;i++){
        int j = jg*8+i;
        tmp[0*32*129 + j*129 + c] = acc0[i];
        tmp[1*32*129 + j*129 + c] = acc0[i] - accS[i];
    }
    __syncthreads();
    {
        int i4 = tid & 7;
        int j  = (tid>>3) & 31;
        int p  = tid >> 8;
        float a0=0.f,a1=0.f,a2=0.f,a3=0.f;
        for(int cc=0; cc<ABDIM; cc++){
            float tv = tmp[p*32*129 + j*129 + cc];
            float4 fx = *(const float4*)&sFxT[cc*32 + i4*4];
            a0 += tv*fx.x; a1 += tv*fx.y; a2 += tv*fx.z; a3 += tv*fx.w;
        }
        float ov[4] = {gamma*a0, gamma*a1, gamma*a2, gamma*a3};
        ushort4 oh, ol; ushort hq;
        hq=f2bf_rne(ov[0]); oh.x=hq; ol.x=f2bf_rne(ov[0]-bf2f(hq));
        hq=f2bf_rne(ov[1]); oh.y=hq; ol.y=f2bf_rne(ov[1]-bf2f(hq));
        hq=f2bf_rne(ov[2]); oh.z=hq; ol.z=f2bf_rne(ov[2]-bf2f(hq));
        hq=f2bf_rne(ov[3]); oh.w=hq; ol.w=f2bf_rne(ov[3]-bf2f(hq));
        size_t off = (size_t)bb*ENCIN + p*1024 + j*NGRID + i4*4;
        *(ushort4*)(Eh + off) = oh;
        *(ushort4*)(El + off) = ol;
    }
    {
        int i = tid;
        Eh[(size_t)bb*ENCIN + 2048 + i] = Hd_h[(size_t)bb*HDIM + i];
        El[(size_t)bb*ENCIN + 2048 + i] = Hd_l[(size_t)bb*HDIM + i];
    }
}

// ---- one MFMA GEMM tile (split-bf16, 3 products), 64x64, 256thr, BK=64 ----
__device__ void gemm_one(const ushort* __restrict__ Agh, const ushort* __restrict__ Agl,
        const ushort* __restrict__ Wh, const ushort* __restrict__ Wl,
        int K, int k0, int kiters, int row0, int col0, int Nn, float* __restrict__ Out,
        ushort* AH, ushort* AL, ushort* BH, ushort* BL, int tid){
    int lane = tid&63, w = tid>>6;
    int m0 = (w>>1)*32, n0 = (w&1)*32;
    int fr = lane&15, kq = (lane>>4)*8;
    int sr = tid>>2, sq = (tid&3)*16;
    f32x4 acc[2][2];
    #pragma unroll
    for(int i=0;i<2;i++)
        #pragma unroll
        for(int j=0;j<2;j++) acc[i][j]=(f32x4){0.f,0.f,0.f,0.f};
    for(int it=0; it<kiters; ++it){
        int kb = k0 + it*64;
        size_t aoff = (size_t)(row0+sr)*K + kb + sq;
        size_t boff = (size_t)(col0+sr)*K + kb + sq;
        uint4 ah0 = *(const uint4*)(Agh + aoff);
        uint4 ah1 = *(const uint4*)(Agh + aoff + 8);
        uint4 al0 = *(const uint4*)(Agl + aoff);
        uint4 al1 = *(const uint4*)(Agl + aoff + 8);
        uint4 bh0 = *(const uint4*)(Wh + boff);
        uint4 bh1 = *(const uint4*)(Wh + boff + 8);
        uint4 bl0 = *(const uint4*)(Wl + boff);
        uint4 bl1 = *(const uint4*)(Wl + boff + 8);
        __syncthreads();
        *(uint4*)&AH[sr*72 + sq]     = ah0;
        *(uint4*)&AH[sr*72 + sq + 8] = ah1;
        *(uint4*)&AL[sr*72 + sq]     = al0;
        *(uint4*)&AL[sr*72 + sq + 8] = al1;
        *(uint4*)&BH[sr*72 + sq]     = bh0;
        *(uint4*)&BH[sr*72 + sq + 8] = bh1;
        *(uint4*)&BL[sr*72 + sq]     = bl0;
        *(uint4*)&BL[sr*72 + sq + 8] = bl1;
        __syncthreads();
        #pragma unroll
        for(int ks=0; ks<2; ks++){
            int kk = ks*32 + kq;
            short8 a_h[2], a_l[2], b_h[2], b_l[2];
            #pragma unroll
            for(int mf=0;mf<2;mf++){
                a_h[mf] = *(short8*)&AH[(m0+mf*16+fr)*72 + kk];
                a_l[mf] = *(short8*)&AL[(m0+mf*16+fr)*72 + kk];
            }
            #pragma unroll
            for(int nf=0;nf<2;nf++){
                b_h[nf] = *(short8*)&BH[(n0+nf*16+fr)*72 + kk];
                b_l[nf] = *(short8*)&BL[(n0+nf*16+fr)*72 + kk];
            }
            #pragma unroll
            for(int mf=0;mf<2;mf++)
                #pragma unroll
                for(int nf=0;nf<2;nf++){
                    acc[mf][nf] = __builtin_amdgcn_mfma_f32_16x16x32_bf16(a_h[mf], b_h[nf], acc[mf][nf], 0,0,0);
                    acc[mf][nf] = __builtin_amdgcn_mfma_f32_16x16x32_bf16(a_h[mf], b_l[nf], acc[mf][nf], 0,0,0);
                    acc[mf][nf] = __builtin_amdgcn_mfma_f32_16x16x32_bf16(a_l[mf], b_h[nf], acc[mf][nf], 0,0,0);
                }
        }
    }
    int crow = (lane>>4)*4, ccol = lane&15;
    #pragma unroll
    for(int mf=0;mf<2;mf++)
        #pragma unroll
        for(int nf=0;nf<2;nf++)
            #pragma unroll
            for(int r=0;r<4;r++)
                Out[(size_t)(row0+m0+mf*16+crow+r)*Nn + col0+n0+nf*16+ccol] = acc[mf][nf][r];
}

// job pool: enc-i splitk4 (384 jobs @10 it) + enc-h (96 @8) + dec-h (96 @8) = 576 blocks
__global__ __launch_bounds__(256) void gemm3_k(
        const ushort* __restrict__ Eh, const ushort* __restrict__ El,
        const ushort* __restrict__ Wie_h, const ushort* __restrict__ Wie_l,
        const ushort* __restrict__ He_h, const ushort* __restrict__ He_l,
        const ushort* __restrict__ Whe_h, const ushort* __restrict__ Whe_l,
        const ushort* __restrict__ Hd_h, const ushort* __restrict__ Hd_l,
        const ushort* __restrict__ Whd_h, const ushort* __restrict__ Whd_l,
        float* __restrict__ Pi, float* __restrict__ Ph, float* __restrict__ Ph2){
    __shared__ ushort AH[64*72], AL[64*72], BH[64*72], BL[64*72];
    int job = blockIdx.x, tid = threadIdx.x;
    if(job < 384){
        int tile = job % 96, s = job / 96;
        gemm_one(Eh, El, Wie_h, Wie_l, ENCIN, s*640, 10,
                 (tile/24)*64, (tile%24)*64, G3, Pi + (size_t)s*SLAB, AH, AL, BH, BL, tid);
    } else if(job < 480){
        int tile = job - 384;
        gemm_one(He_h, He_l, Whe_h, Whe_l, HDIM, 0, 8,
                 (tile/24)*64, (tile%24)*64, G3, Ph, AH, AL, BH, BL, tid);
    } else {
        int tile = job - 480;
        gemm_one(Hd_h, Hd_l, Whd_h, Whd_l, HDIM, 0, 8,
                 (tile/24)*64, (tile%24)*64, G3, Ph2, AH, AL, BH, BL, tid);
    }
}

// write GEMM: grid (16 cols, 4 rows, 4 splits), 64x64 tiles, K=512
__global__ __launch_bounds__(256) void gemm_wr_k(
        const ushort* __restrict__ Hd_h, const ushort* __restrict__ Hd_l,
        const ushort* __restrict__ Wwr_h, const ushort* __restrict__ Wwr_l,
        float* __restrict__ Pw){
    __shared__ ushort AH[64*72], AL[64*72], BH[64*72], BL[64*72];
    int tid = threadIdx.x;
    int r0 = blockIdx.y*64, c0 = blockIdx.x*64, s = blockIdx.z;
    gemm_one(Hd_h, Hd_l, Wwr_h, Wwr_l, HDIM, s*128, 2, r0, c0, 1024,
             Pw + (size_t)s*BATCHN*1024, AH, AL, BH, BL, tid);
}

// encoder combine (4 Pi + 1 Ph) + z sample -> Zh/Zl mirrors
__global__ __launch_bounds__(512) void combine_z_k(const float* __restrict__ Pi, const float* __restrict__ Ph,
        const float* __restrict__ bi, const float* __restrict__ bh,
        float* __restrict__ h, ushort* __restrict__ Hh, ushort* __restrict__ Hl,
        const float* __restrict__ Wmu, const float* __restrict__ bmu,
        const float* __restrict__ Wls, const float* __restrict__ bls,
        const float* __restrict__ eps_t, ushort* __restrict__ Zh, ushort* __restrict__ Zl){
    __shared__ float hs[HDIM];
    int bb = blockIdx.x, tid = threadIdx.x;
    int j = tid;
    float gi_r=bi[j], gi_z=bi[512+j], gi_n=bi[1024+j];
    float gh_r=bh[j], gh_z=bh[512+j], gh_n=bh[1024+j];
    #pragma unroll
    for(int s=0;s<4;s++){
        size_t base = (size_t)s*SLAB + (size_t)bb*G3 + j;
        gi_r += Pi[base]; gi_z += Pi[base+512]; gi_n += Pi[base+1024];
    }
    {
        size_t base = (size_t)bb*G3 + j;
        gh_r += Ph[base]; gh_z += Ph[base+512]; gh_n += Ph[base+1024];
    }
    float r = sigmoidf_(gi_r + gh_r);
    float z = sigmoidf_(gi_z + gh_z);
    float n = tanhf(gi_n + r*gh_n);
    size_t hoff = (size_t)bb*HDIM + j;
    float hn = (1.f - z)*n + z*h[hoff];
    h[hoff] = hn; hs[j] = hn;
    ushort hh = f2bf_rne(hn);
    Hh[hoff] = hh; Hl[hoff] = f2bf_rne(hn - bf2f(hh));
    __syncthreads();
    {
        int jo = tid>>2, l4 = tid&3;
        float am=0.f, al_=0.f;
        for(int k=l4;k<HDIM;k+=4){
            float hv = hs[k];
            am  += hv*Wmu[(size_t)jo*HDIM+k];
            al_ += hv*Wls[(size_t)jo*HDIM+k];
        }
        am  += __shfl_xor(am,1);  am  += __shfl_xor(am,2);
        al_ += __shfl_xor(al_,1); al_ += __shfl_xor(al_,2);
        if(l4==0){
            float mu = am + bmu[jo];
            float sg = expf(al_ + bls[jo]);
            float zv = mu + eps_t[(size_t)bb*ZDIM + jo]*sg;
            ushort zh = f2bf_rne(zv);
            Zh[(size_t)bb*ZDIM + jo] = zh;
            Zl[(size_t)bb*ZDIM + jo] = f2bf_rne(zv - bf2f(zh));
        }
    }
}

// dec-i MFMA (Z @ Wid^T, gates r/z/n) fused with decoder GRU combine
// grid (8 j-col-groups, 4 batch-row-groups); 256 thr
__global__ __launch_bounds__(256) void deci_combine_k(
        const ushort* __restrict__ Zh, const ushort* __restrict__ Zl,
        const ushort* __restrict__ Wid_h, const ushort* __restrict__ Wid_l,
        const float* __restrict__ Ph2, const float* __restrict__ bi, const float* __restrict__ bh,
        float* __restrict__ h, ushort* __restrict__ Hh, ushort* __restrict__ Hl){
    __shared__ ushort AH[64*72], AL[64*72], BH[64*72], BL[64*72];
    int tid = threadIdx.x;
    int lane = tid&63, w = tid>>6;
    int m0 = (w>>1)*32, n0 = (w&1)*32;
    int fr = lane&15, kq = (lane>>4)*8;
    int sr = tid>>2, sq = (tid&3)*16;
    int row0 = blockIdx.y*64;           // batch rows
    int jcol0 = blockIdx.x*64;          // hidden j cols (0..511)
    f32x4 acc[3][2][2];
    #pragma unroll
    for(int g=0;g<3;g++)
        #pragma unroll
        for(int i=0;i<2;i++)
            #pragma unroll
            for(int jj=0;jj<2;jj++) acc[g][i][jj]=(f32x4){0.f,0.f,0.f,0.f};
    for(int it=0; it<2; ++it){
        int kb = it*64;
        size_t aoff = (size_t)(row0+sr)*ZDIM + kb + sq;
        uint4 ah0 = *(const uint4*)(Zh + aoff);
        uint4 ah1 = *(const uint4*)(Zh + aoff + 8);
        uint4 al0 = *(const uint4*)(Zl + aoff);
        uint4 al1 = *(const uint4*)(Zl + aoff + 8);
        __syncthreads();        // prior gate's frag reads complete
        *(uint4*)&AH[sr*72 + sq]     = ah0;
        *(uint4*)&AH[sr*72 + sq + 8] = ah1;
        *(uint4*)&AL[sr*72 + sq]     = al0;
        *(uint4*)&AL[sr*72 + sq + 8] = al1;
        for(int g=0; g<3; ++g){
            size_t boff = (size_t)(g*512 + jcol0 + sr)*ZDIM + kb + sq;
            uint4 bh0 = *(const uint4*)(Wid_h + boff);
            uint4 bh1 = *(const uint4*)(Wid_h + boff + 8);
            uint4 bl0 = *(const uint4*)(Wid_l + boff);
            uint4 bl1 = *(const uint4*)(Wid_l + boff + 8);
            if(g>0) __syncthreads();    // prior gate done reading BH/BL
            *(uint4*)&BH[sr*72 + sq]     = bh0;
            *(uint4*)&BH[sr*72 + sq + 8] = bh1;
            *(uint4*)&BL[sr*72 + sq]     = bl0;
            *(uint4*)&BL[sr*72 + sq + 8] = bl1;
            __syncthreads();
            #pragma unroll
            for(int ks=0; ks<2; ks++){
                int kk = ks*32 + kq;
                short8 a_h[2], a_l[2], b_h[2], b_l[2];
                #pragma unroll
                for(int mf=0;mf<2;mf++){
                    a_h[mf] = *(short8*)&AH[(m0+mf*16+fr)*72 + kk];
                    a_l[mf] = *(short8*)&AL[(m0+mf*16+fr)*72 + kk];
                }
                #pragma unroll
                for(int nf=0;nf<2;nf++){
                    b_h[nf] = *(short8*)&BH[(n0+nf*16+fr)*72 + kk];
                    b_l[nf] = *(short8*)&BL[(n0+nf*16+fr)*72 + kk];
                }
                #pragma unroll
                for(int mf=0;mf<2;mf++)
                    #pragma unroll
                    for(int nf=0;nf<2;nf++){
                        acc[g][mf][nf] = __builtin_amdgcn_mfma_f32_16x16x32_bf16(a_h[mf], b_h[nf], acc[g][mf][nf], 0,0,0);
                        acc[g][mf][nf] = __builtin_amdgcn_mfma_f32_16x16x32_bf16(a_h[mf], b_l[nf], acc[g][mf][nf], 0,0,0);
                        acc[g][mf][nf] = __builtin_amdgcn_mfma_f32_16x16x32_bf16(a_l[mf], b_h[nf], acc[g][mf][nf], 0,0,0);
                    }
            }
        }
    }
    // epilogue: GRU combine directly from accumulators
    int crow = (lane>>4)*4, ccol = lane&15;
    #pragma unroll
    for(int mf=0;mf<2;mf++)
        #pragma unroll
        for(int nf=0;nf<2;nf++)
            #pragma unroll
            for(int r=0;r<4;r++){
                int row = row0 + m0 + mf*16 + crow + r;     // batch
                int col = jcol0 + n0 + nf*16 + ccol;        // j
                size_t pbase = (size_t)row*G3 + col;
                float gi_r = acc[0][mf][nf][r] + bi[col];
                float gi_z = acc[1][mf][nf][r] + bi[512+col];
                float gi_n = acc[2][mf][nf][r] + bi[1024+col];
                float gh_r = Ph2[pbase]      + bh[col];
                float gh_z = Ph2[pbase+512]  + bh[512+col];
                float gh_n = Ph2[pbase+1024] + bh[1024+col];
                float rr = sigmoidf_(gi_r + gh_r);
                float zz = sigmoidf_(gi_z + gh_z);
                float nn = tanhf(gi_n + rr*gh_n);
                size_t idx = (size_t)row*HDIM + col;
                float hn = (1.f - zz)*nn + zz*h[idx];
                h[idx] = hn;
                ushort hh = f2bf_rne(hn);
                Hh[idx] = hh; Hl[idx] = f2bf_rne(hn - bf2f(hh));
            }
}

// write path: params+filterbank+reduce(Pw,4 slabs)+apply; refresh s_last; 512 threads
__global__ __launch_bounds__(512) void write_apply_k(const float* __restrict__ Pw, const float* __restrict__ b_wr,
        const float* __restrict__ hdec, const float* __restrict__ W_wa, const float* __restrict__ b_wa,
        float* __restrict__ rec, float* __restrict__ s_last){
    __shared__ float sFy[NGRID][ABDIM+1];
    __shared__ float sFx[NGRID][ABDIM+1];
    __shared__ float sw[NGRID][36];
    __shared__ float t[ABDIM][36];
    __shared__ float red5[40];
    __shared__ float pp[8];
    int bb = blockIdx.x, tid = threadIdx.x;
    const float* h = hdec + bb*HDIM;
    attn_params_dev512(h, W_wa, b_wa, red5, pp, tid);
    float invg = expf(-pp[4]);
    fill_fb_R(sFx, sFy, pp, tid);
    for(int i=tid;i<NGRID*NGRID;i+=512){
        float a = b_wr[i];
        #pragma unroll
        for(int s=0;s<4;s++) a += Pw[((size_t)s*BATCHN + bb)*1024 + i];
        sw[i>>5][i&31] = a;
    }
    __syncthreads();
    {
        int p = tid>>2, iq = tid&3;
        float a[8];
        #pragma unroll
        for(int i=0;i<8;i++) a[i]=0.f;
        for(int j=0;j<NGRID;j++){
            float fy = sFy[j][p];
            float4 w0 = *(const float4*)&sw[j][iq*8];
            float4 w1 = *(const float4*)&sw[j][iq*8+4];
            a[0]+=fy*w0.x; a[1]+=fy*w0.y; a[2]+=fy*w0.z; a[3]+=fy*w0.w;
            a[4]+=fy*w1.x; a[5]+=fy*w1.y; a[6]+=fy*w1.z; a[7]+=fy*w1.w;
        }
        float4 o0; o0.x=a[0];o0.y=a[1];o0.z=a[2];o0.w=a[3];
        float4 o1; o1.x=a[4];o1.y=a[5];o1.z=a[6];o1.w=a[7];
        *(float4*)&t[p][iq*8]   = o0;
        *(float4*)&t[p][iq*8+4] = o1;
    }
    __syncthreads();
    {
        int q = tid&127, pg = tid>>7;
        float fxc[32];
        #pragma unroll
        for(int i=0;i<32;i++) fxc[i] = sFx[i][q];
        for(int pi=0; pi<32; pi++){
            int p = pg*32 + pi;
            float acc = 0.f;
            #pragma unroll
            for(int i4=0;i4<8;i4++){
                float4 tv = *(const float4*)&t[p][i4*4];
                acc += tv.x*fxc[i4*4] + tv.y*fxc[i4*4+1] + tv.z*fxc[i4*4+2] + tv.w*fxc[i4*4+3];
            }
            size_t off = (size_t)bb*IMGSZ + p*ABDIM + q;
            float nv = rec[off] + acc*invg;
            rec[off] = nv;
            if(bb==BATCHN-1) s_last[p*ABDIM + q] = sigmoidf_(nv);
        }
    }
}

__global__ void sigmoid_all_k(float* __restrict__ rec){
    int i = blockIdx.x*256 + threadIdx.x;
    rec[i] = sigmoidf_(rec[i]);
}

extern "C" void kernel_launch(void* const* d_in, const int* in_sizes, int n_in,
                              void* d_out, int out_size, void* d_ws, size_t ws_size,
                              hipStream_t stream) {
    const float* x        = (const float*)d_in[0];
    const float* eps      = (const float*)d_in[1];
    const float* W_ih_enc = (const float*)d_in[2];
    const float* W_hh_enc = (const float*)d_in[3];
    const float* b_ih_enc = (const float*)d_in[4];
    const float* b_hh_enc = (const float*)d_in[5];
    const float* W_ih_dec = (const float*)d_in[6];
    const float* W_hh_dec = (const float*)d_in[7];
    const float* b_ih_dec = (const float*)d_in[8];
    const float* b_hh_dec = (const float*)d_in[9];
    const float* W_mu     = (const float*)d_in[10];
    const float* b_mu     = (const float*)d_in[11];
    const float* W_ls     = (const float*)d_in[12];
    const float* b_ls     = (const float*)d_in[13];
    const float* W_wr     = (const float*)d_in[14];
    const float* b_wr     = (const float*)d_in[15];
    const float* W_ra     = (const float*)d_in[16];
    const float* b_ra     = (const float*)d_in[17];
    const float* W_wa     = (const float*)d_in[18];
    const float* b_wa     = (const float*)d_in[19];

    float* rec = (float*)d_out;

    float* ws = (float*)d_ws;
    float* h_enc  = ws;  ws += BATCHN*HDIM;
    float* h_dec  = ws;  ws += BATCHN*HDIM;
    float* s_last = ws;  ws += IMGSZ;
    float* Pi     = ws;  ws += (size_t)4*SLAB;
    float* Ph     = ws;  ws += (size_t)SLAB;
    float* Ph2    = ws;  ws += (size_t)SLAB;
    float* Pw     = ws;  ws += (size_t)4*BATCHN*1024;

    ushort* us = (ushort*)ws;
    ushort* Wie_h = us; us += 1536*2560;
    ushort* Wie_l = us; us += 1536*2560;
    ushort* Whe_h = us; us += 1536*512;
    ushort* Whe_l = us; us += 1536*512;
    ushort* Whd_h = us; us += 1536*512;
    ushort* Whd_l = us; us += 1536*512;
    ushort* Wid_h = us; us += 1536*128;
    ushort* Wid_l = us; us += 1536*128;
    ushort* Wwr_h = us; us += 1024*512;
    ushort* Wwr_l = us; us += 1024*512;
    ushort* Eh    = us; us += BATCHN*ENCIN;
    ushort* El    = us; us += BATCHN*ENCIN;
    ushort* He_h  = us; us += BATCHN*HDIM;
    ushort* He_l  = us; us += BATCHN*HDIM;
    ushort* Hd_h  = us; us += BATCHN*HDIM;
    ushort* Hd_l  = us; us += BATCHN*HDIM;
    ushort* Zh    = us; us += BATCHN*ZDIM;
    ushort* Zl    = us; us += BATCHN*ZDIM;

    hipMemsetAsync(rec,   0, (size_t)BATCHN*IMGSZ*sizeof(float), stream);
    hipMemsetAsync(h_enc, 0, (size_t)BATCHN*HDIM*sizeof(float), stream);
    hipMemsetAsync(h_dec, 0, (size_t)BATCHN*HDIM*sizeof(float), stream);
    hipMemsetAsync(He_h,  0, (size_t)BATCHN*HDIM*sizeof(ushort)*2, stream);  // He_h+He_l contiguous
    hipMemsetAsync(Hd_h,  0, (size_t)BATCHN*HDIM*sizeof(ushort)*2, stream);  // Hd_h+Hd_l contiguous
    init_slast_k<<<IMGSZ/256,256,0,stream>>>(s_last);

    conv_w_k<<<(1536*2560/4+255)/256,256,0,stream>>>(W_ih_enc, Wie_h, Wie_l, 1536*2560/4);
    conv_w_k<<<(1536*512/4+255)/256,256,0,stream>>>(W_hh_enc, Whe_h, Whe_l, 1536*512/4);
    conv_w_k<<<(1536*512/4+255)/256,256,0,stream>>>(W_hh_dec, Whd_h, Whd_l, 1536*512/4);
    conv_w_k<<<(1536*128/4+255)/256,256,0,stream>>>(W_ih_dec, Wid_h, Wid_l, 1536*128/4);
    conv_w_k<<<(1024*512/4+255)/256,256,0,stream>>>(W_wr, Wwr_h, Wwr_l, 1024*512/4);

    for(int t=0;t<16;t++){
        read_attn_k<<<BATCHN,512,0,stream>>>(x, s_last, h_dec, Hd_h, Hd_l, W_ra, b_ra, Eh, El);
        gemm3_k<<<576,256,0,stream>>>(Eh, El, Wie_h, Wie_l, He_h, He_l, Whe_h, Whe_l,
                                      Hd_h, Hd_l, Whd_h, Whd_l, Pi, Ph, Ph2);
        combine_z_k<<<BATCHN,512,0,stream>>>(Pi, Ph, b_ih_enc, b_hh_enc,
            h_enc, He_h, He_l, W_mu, b_mu, W_ls, b_ls, eps + (size_t)t*BATCHN*ZDIM, Zh, Zl);
        deci_combine_k<<<dim3(8,4),256,0,stream>>>(Zh, Zl, Wid_h, Wid_l, Ph2,
            b_ih_dec, b_hh_dec, h_dec, Hd_h, Hd_l);
        gemm_wr_k<<<dim3(16,4,4),256,0,stream>>>(Hd_h, Hd_l, Wwr_h, Wwr_l, Pw);
        write_apply_k<<<BATCHN,512,0,stream>>>(Pw, b_wr, h_dec, W_wa, b_wa, rec, s_last);
    }
    sigmoid_all_k<<<BATCHN*IMGSZ/256,256,0,stream>>>(rec);
}

// Round 9
// 1407.685 us; speedup vs baseline: 3.7488x; 1.1515x over previous
//
#include <hip/hip_runtime.h>
#include <math.h>

#define BATCHN 256
#define HDIM 512
#define ZDIM 128
#define NGRID 32
#define ABDIM 128
#define IMGSZ 16384   // 128*128
#define ENCIN 2560
#define G3 1536
#define SLAB (BATCHN*G3)

typedef __attribute__((ext_vector_type(8))) short short8;
typedef __attribute__((ext_vector_type(4))) float f32x4;

__device__ __forceinline__ float sigmoidf_(float x){ return 1.0f/(1.0f+expf(-x)); }

__device__ __forceinline__ ushort f2bf_rne(float f){
    union{float f; uint u;} x; x.f=f;
    uint r = (x.u + 0x7FFFu + ((x.u>>16)&1u)) >> 16;
    return (ushort)r;
}
__device__ __forceinline__ float bf2f(ushort h){
    union{uint u; float f;} y; y.u = ((uint)h)<<16;
    return y.f;
}

__global__ void init_slast_k(float* __restrict__ s_last){
    int i = blockIdx.x*256 + threadIdx.x;
    s_last[i] = 0.5f;   // sigmoid(0)
}

// convert f32 weights -> bf16 (hi only; weight-lo dropped: 2-product scheme)
__global__ void conv_wh_k(const float* __restrict__ W, ushort* __restrict__ Wh, int n4){
    int i = blockIdx.x*256 + threadIdx.x;
    if(i>=n4) return;
    float4 v = ((const float4*)W)[i];
    ushort4 hv;
    hv.x=f2bf_rne(v.x); hv.y=f2bf_rne(v.y); hv.z=f2bf_rne(v.z); hv.w=f2bf_rne(v.w);
    ((ushort4*)Wh)[i] = hv;
}

// ---- attention params with NT=512 threads ----
__device__ __forceinline__ void attn_params_dev512(const float* __restrict__ h,
        const float* __restrict__ W, const float* __restrict__ bvec,
        float* red5, float* pp, int tid){
    float accp[5];
    #pragma unroll
    for(int i=0;i<5;i++) accp[i]=0.f;
    for(int k=tid;k<HDIM;k+=512){
        float hv = h[k];
        #pragma unroll
        for(int i=0;i<5;i++) accp[i] += hv*W[i*HDIM+k];
    }
    int wv = tid>>6;
    #pragma unroll
    for(int i=0;i<5;i++){
        float a = accp[i];
        #pragma unroll
        for(int o=32;o>0;o>>=1) a += __shfl_down(a,o);
        if((tid&63)==0) red5[i*8+wv]=a;
    }
    __syncthreads();
    if(tid<5){
        float s = bvec[tid];
        #pragma unroll
        for(int w2=0;w2<8;w2++) s += red5[tid*8+w2];
        pp[tid]=s;
    }
    __syncthreads();
}

// transposed fill: fxT[pix][j], fyT[pix][j]; NT=512
__device__ __forceinline__ void fill_fb_T(float* fxT, float* fyT, const float* pp, int tid){
    float gx = 64.5f*(pp[0]+1.0f);
    float gy = 64.5f*(pp[1]+1.0f);
    float tss = 2.0f*expf(pp[2]);
    float delta = (127.0f/31.0f)*expf(pp[3]);
    int rr = tid>>3;
    int q  = tid&7;
    int j  = rr&31;
    bool isY = rr>=32;
    float mu = (isY?gy:gx) + ((float)j-15.5f)*delta;
    float v[16]; float s=0.f;
    #pragma unroll
    for(int i=0;i<16;i++){
        float d = (float)(q*16+i)-mu;
        float e = expf(-d*d/tss);
        v[i]=e; s+=e;
    }
    s += __shfl_xor(s,1); s += __shfl_xor(s,2); s += __shfl_xor(s,4);
    float inv = 1.0f/fmaxf(s,1e-8f);
    float* dst = isY? fyT : fxT;
    #pragma unroll
    for(int i=0;i<16;i++) dst[(q*16+i)*32 + j] = v[i]*inv;
    __syncthreads();
}

// row-major fill: fx[32][129], fy[32][129]; NT=512
__device__ __forceinline__ void fill_fb_R(float (*fx)[ABDIM+1], float (*fy)[ABDIM+1], const float* pp, int tid){
    float gx = 64.5f*(pp[0]+1.0f);
    float gy = 64.5f*(pp[1]+1.0f);
    float tss = 2.0f*expf(pp[2]);
    float delta = (127.0f/31.0f)*expf(pp[3]);
    int rr = tid>>3;
    int q  = tid&7;
    int j  = rr&31;
    bool isY = rr>=32;
    float mu = (isY?gy:gx) + ((float)j-15.5f)*delta;
    float v[16]; float s=0.f;
    #pragma unroll
    for(int i=0;i<16;i++){
        float d = (float)(q*16+i)-mu;
        float e = expf(-d*d/tss);
        v[i]=e; s+=e;
    }
    s += __shfl_xor(s,1); s += __shfl_xor(s,2); s += __shfl_xor(s,4);
    float inv = 1.0f/fmaxf(s,1e-8f);
    float* rowp = isY? &fy[j][0] : &fx[j][0];
    #pragma unroll
    for(int i=0;i<16;i++) rowp[q*16+i] = v[i]*inv;
    __syncthreads();
}

// per-batch fused read attention; 512 threads; writes enc_in as bf16 hi/lo
__global__ __launch_bounds__(512) void read_attn_k(const float* __restrict__ xf, const float* __restrict__ s_last,
        const float* __restrict__ hdec, const ushort* __restrict__ Hd_h, const ushort* __restrict__ Hd_l,
        const float* __restrict__ W_ra, const float* __restrict__ b_ra,
        ushort* __restrict__ Eh, ushort* __restrict__ El){
    __shared__ float smem[4096 + 8256 + 48];
    float* sFxT = smem;
    float* sFyT = smem + 4096;
    float* tmp  = smem + 4096;            // aliases sFyT (barrier-separated)
    float* red5 = smem + 4096 + 8256;
    float* pp   = red5 + 40;
    int bb = blockIdx.x; int tid = threadIdx.x;
    const float* h = hdec + bb*HDIM;
    attn_params_dev512(h, W_ra, b_ra, red5, pp, tid);
    float gamma = expf(pp[4]);
    fill_fb_T(sFxT, sFyT, pp, tid);

    const float* img = xf + (size_t)bb*IMGSZ;
    int c = tid & 127;
    int jg = tid >> 7;
    float acc0[8], accS[8];
    #pragma unroll
    for(int i=0;i<8;i++){ acc0[i]=0.f; accS[i]=0.f; }
    for(int k=0;k<ABDIM;k++){
        float s  = img[k*ABDIM + c];
        float sl = s_last[k*ABDIM + c];
        float4 f0 = *(const float4*)&sFyT[k*32 + jg*8];
        float4 f1 = *(const float4*)&sFyT[k*32 + jg*8 + 4];
        acc0[0]+=f0.x*s;  acc0[1]+=f0.y*s;  acc0[2]+=f0.z*s;  acc0[3]+=f0.w*s;
        acc0[4]+=f1.x*s;  acc0[5]+=f1.y*s;  acc0[6]+=f1.z*s;  acc0[7]+=f1.w*s;
        accS[0]+=f0.x*sl; accS[1]+=f0.y*sl; accS[2]+=f0.z*sl; accS[3]+=f0.w*sl;
        accS[4]+=f1.x*sl; accS[5]+=f1.y*sl; accS[6]+=f1.z*sl; accS[7]+=f1.w*sl;
    }
    __syncthreads();
    #pragma unroll
    for(int i=0;i<8;i++){
        int j = jg*8+i;
        tmp[0*32*129 + j*129 + c] = acc0[i];
        tmp[1*32*129 + j*129 + c] = acc0[i] - accS[i];
    }
    __syncthreads();
    {
        int i4 = tid & 7;
        int j  = (tid>>3) & 31;
        int p  = tid >> 8;
        float a0=0.f,a1=0.f,a2=0.f,a3=0.f;
        for(int cc=0; cc<ABDIM; cc++){
            float tv = tmp[p*32*129 + j*129 + cc];
            float4 fx = *(const float4*)&sFxT[cc*32 + i4*4];
            a0 += tv*fx.x; a1 += tv*fx.y; a2 += tv*fx.z; a3 += tv*fx.w;
        }
        float ov[4] = {gamma*a0, gamma*a1, gamma*a2, gamma*a3};
        ushort4 oh, ol; ushort hq;
        hq=f2bf_rne(ov[0]); oh.x=hq; ol.x=f2bf_rne(ov[0]-bf2f(hq));
        hq=f2bf_rne(ov[1]); oh.y=hq; ol.y=f2bf_rne(ov[1]-bf2f(hq));
        hq=f2bf_rne(ov[2]); oh.z=hq; ol.z=f2bf_rne(ov[2]-bf2f(hq));
        hq=f2bf_rne(ov[3]); oh.w=hq; ol.w=f2bf_rne(ov[3]-bf2f(hq));
        size_t off = (size_t)bb*ENCIN + p*1024 + j*NGRID + i4*4;
        *(ushort4*)(Eh + off) = oh;
        *(ushort4*)(El + off) = ol;
    }
    {
        int i = tid;
        Eh[(size_t)bb*ENCIN + 2048 + i] = Hd_h[(size_t)bb*HDIM + i];
        El[(size_t)bb*ENCIN + 2048 + i] = Hd_l[(size_t)bb*HDIM + i];
    }
}

// ---- one MFMA GEMM tile (2-product split-bf16: (ahi+alo)*bhi), 64x64, 256thr, BK=64 ----
__device__ void gemm_one(const ushort* __restrict__ Agh, const ushort* __restrict__ Agl,
        const ushort* __restrict__ Wh,
        int K, int k0, int kiters, int row0, int col0, int Nn, float* __restrict__ Out,
        ushort* AH, ushort* AL, ushort* BH, int tid){
    int lane = tid&63, w = tid>>6;
    int m0 = (w>>1)*32, n0 = (w&1)*32;
    int fr = lane&15, kq = (lane>>4)*8;
    int sr = tid>>2, sq = (tid&3)*16;
    f32x4 acc[2][2];
    #pragma unroll
    for(int i=0;i<2;i++)
        #pragma unroll
        for(int j=0;j<2;j++) acc[i][j]=(f32x4){0.f,0.f,0.f,0.f};
    for(int it=0; it<kiters; ++it){
        int kb = k0 + it*64;
        size_t aoff = (size_t)(row0+sr)*K + kb + sq;
        size_t boff = (size_t)(col0+sr)*K + kb + sq;
        uint4 ah0 = *(const uint4*)(Agh + aoff);
        uint4 ah1 = *(const uint4*)(Agh + aoff + 8);
        uint4 al0 = *(const uint4*)(Agl + aoff);
        uint4 al1 = *(const uint4*)(Agl + aoff + 8);
        uint4 bh0 = *(const uint4*)(Wh + boff);
        uint4 bh1 = *(const uint4*)(Wh + boff + 8);
        __syncthreads();
        *(uint4*)&AH[sr*72 + sq]     = ah0;
        *(uint4*)&AH[sr*72 + sq + 8] = ah1;
        *(uint4*)&AL[sr*72 + sq]     = al0;
        *(uint4*)&AL[sr*72 + sq + 8] = al1;
        *(uint4*)&BH[sr*72 + sq]     = bh0;
        *(uint4*)&BH[sr*72 + sq + 8] = bh1;
        __syncthreads();
        #pragma unroll
        for(int ks=0; ks<2; ks++){
            int kk = ks*32 + kq;
            short8 a_h[2], a_l[2], b_h[2];
            #pragma unroll
            for(int mf=0;mf<2;mf++){
                a_h[mf] = *(short8*)&AH[(m0+mf*16+fr)*72 + kk];
                a_l[mf] = *(short8*)&AL[(m0+mf*16+fr)*72 + kk];
            }
            #pragma unroll
            for(int nf=0;nf<2;nf++)
                b_h[nf] = *(short8*)&BH[(n0+nf*16+fr)*72 + kk];
            #pragma unroll
            for(int mf=0;mf<2;mf++)
                #pragma unroll
                for(int nf=0;nf<2;nf++){
                    acc[mf][nf] = __builtin_amdgcn_mfma_f32_16x16x32_bf16(a_h[mf], b_h[nf], acc[mf][nf], 0,0,0);
                    acc[mf][nf] = __builtin_amdgcn_mfma_f32_16x16x32_bf16(a_l[mf], b_h[nf], acc[mf][nf], 0,0,0);
                }
        }
    }
    int crow = (lane>>4)*4, ccol = lane&15;
    #pragma unroll
    for(int mf=0;mf<2;mf++)
        #pragma unroll
        for(int nf=0;nf<2;nf++)
            #pragma unroll
            for(int r=0;r<4;r++)
                Out[(size_t)(row0+m0+mf*16+crow+r)*Nn + col0+n0+nf*16+ccol] = acc[mf][nf][r];
}

// job pool: enc-i splitk4 (384 jobs @10 it) + enc-h (96 @8) + dec-h (96 @8) = 576 blocks
__global__ __launch_bounds__(256) void gemm3_k(
        const ushort* __restrict__ Eh, const ushort* __restrict__ El,
        const ushort* __restrict__ Wie_h,
        const ushort* __restrict__ He_h, const ushort* __restrict__ He_l,
        const ushort* __restrict__ Whe_h,
        const ushort* __restrict__ Hd_h, const ushort* __restrict__ Hd_l,
        const ushort* __restrict__ Whd_h,
        float* __restrict__ Pi, float* __restrict__ Ph, float* __restrict__ Ph2){
    __shared__ ushort AH[64*72], AL[64*72], BH[64*72];
    int job = blockIdx.x, tid = threadIdx.x;
    if(job < 384){
        int tile = job % 96, s = job / 96;
        gemm_one(Eh, El, Wie_h, ENCIN, s*640, 10,
                 (tile/24)*64, (tile%24)*64, G3, Pi + (size_t)s*SLAB, AH, AL, BH, tid);
    } else if(job < 480){
        int tile = job - 384;
        gemm_one(He_h, He_l, Whe_h, HDIM, 0, 8,
                 (tile/24)*64, (tile%24)*64, G3, Ph, AH, AL, BH, tid);
    } else {
        int tile = job - 480;
        gemm_one(Hd_h, Hd_l, Whd_h, HDIM, 0, 8,
                 (tile/24)*64, (tile%24)*64, G3, Ph2, AH, AL, BH, tid);
    }
}

// write GEMM: grid (16 cols, 4 rows, 4 splits), 64x64 tiles, K=512
__global__ __launch_bounds__(256) void gemm_wr_k(
        const ushort* __restrict__ Hd_h, const ushort* __restrict__ Hd_l,
        const ushort* __restrict__ Wwr_h,
        float* __restrict__ Pw){
    __shared__ ushort AH[64*72], AL[64*72], BH[64*72];
    int tid = threadIdx.x;
    int r0 = blockIdx.y*64, c0 = blockIdx.x*64, s = blockIdx.z;
    gemm_one(Hd_h, Hd_l, Wwr_h, HDIM, s*128, 2, r0, c0, 1024,
             Pw + (size_t)s*BATCHN*1024, AH, AL, BH, tid);
}

// encoder combine (4 Pi + 1 Ph) + z sample -> Zh/Zl mirrors
__global__ __launch_bounds__(512) void combine_z_k(const float* __restrict__ Pi, const float* __restrict__ Ph,
        const float* __restrict__ bi, const float* __restrict__ bh,
        float* __restrict__ h, ushort* __restrict__ Hh, ushort* __restrict__ Hl,
        const float* __restrict__ Wmu, const float* __restrict__ bmu,
        const float* __restrict__ Wls, const float* __restrict__ bls,
        const float* __restrict__ eps_t, ushort* __restrict__ Zh, ushort* __restrict__ Zl){
    __shared__ float hs[HDIM];
    int bb = blockIdx.x, tid = threadIdx.x;
    int j = tid;
    float gi_r=bi[j], gi_z=bi[512+j], gi_n=bi[1024+j];
    float gh_r=bh[j], gh_z=bh[512+j], gh_n=bh[1024+j];
    #pragma unroll
    for(int s=0;s<4;s++){
        size_t base = (size_t)s*SLAB + (size_t)bb*G3 + j;
        gi_r += Pi[base]; gi_z += Pi[base+512]; gi_n += Pi[base+1024];
    }
    {
        size_t base = (size_t)bb*G3 + j;
        gh_r += Ph[base]; gh_z += Ph[base+512]; gh_n += Ph[base+1024];
    }
    float r = sigmoidf_(gi_r + gh_r);
    float z = sigmoidf_(gi_z + gh_z);
    float n = tanhf(gi_n + r*gh_n);
    size_t hoff = (size_t)bb*HDIM + j;
    float hn = (1.f - z)*n + z*h[hoff];
    h[hoff] = hn; hs[j] = hn;
    ushort hh = f2bf_rne(hn);
    Hh[hoff] = hh; Hl[hoff] = f2bf_rne(hn - bf2f(hh));
    __syncthreads();
    // z sample: wave per output; lane reads 32B contiguous of each weight row (coalesced)
    {
        int wv = tid>>6, lane = tid&63;
        const float4* hs4 = (const float4*)hs;
        float4 h0 = hs4[lane*2];
        float4 h1 = hs4[lane*2+1];
        #pragma unroll 4
        for(int it=0; it<16; ++it){
            int jo = wv*16 + it;
            const float4* wm = (const float4*)(Wmu + (size_t)jo*HDIM);
            const float4* wl = (const float4*)(Wls + (size_t)jo*HDIM);
            float4 m0=wm[lane*2], m1=wm[lane*2+1];
            float4 l0=wl[lane*2], l1=wl[lane*2+1];
            float am  = h0.x*m0.x+h0.y*m0.y+h0.z*m0.z+h0.w*m0.w
                      + h1.x*m1.x+h1.y*m1.y+h1.z*m1.z+h1.w*m1.w;
            float al_ = h0.x*l0.x+h0.y*l0.y+h0.z*l0.z+h0.w*l0.w
                      + h1.x*l1.x+h1.y*l1.y+h1.z*l1.z+h1.w*l1.w;
            #pragma unroll
            for(int o=32;o>0;o>>=1){ am += __shfl_down(am,o); al_ += __shfl_down(al_,o); }
            if(lane==0){
                float mu = am + bmu[jo];
                float sg = expf(al_ + bls[jo]);
                float zv = mu + eps_t[(size_t)bb*ZDIM + jo]*sg;
                ushort zh = f2bf_rne(zv);
                Zh[(size_t)bb*ZDIM + jo] = zh;
                Zl[(size_t)bb*ZDIM + jo] = f2bf_rne(zv - bf2f(zh));
            }
        }
    }
}

// dec-i MFMA (Z @ Wid^T, gates r/z/n) fused with decoder GRU combine; 2-product
// grid (8 j-col-groups, 4 batch-row-groups); 256 thr
__global__ __launch_bounds__(256) void deci_combine_k(
        const ushort* __restrict__ Zh, const ushort* __restrict__ Zl,
        const ushort* __restrict__ Wid_h,
        const float* __restrict__ Ph2, const float* __restrict__ bi, const float* __restrict__ bh,
        float* __restrict__ h, ushort* __restrict__ Hh, ushort* __restrict__ Hl){
    __shared__ ushort AH[64*72], AL[64*72], BH[64*72];
    int tid = threadIdx.x;
    int lane = tid&63, w = tid>>6;
    int m0 = (w>>1)*32, n0 = (w&1)*32;
    int fr = lane&15, kq = (lane>>4)*8;
    int sr = tid>>2, sq = (tid&3)*16;
    int row0 = blockIdx.y*64;           // batch rows
    int jcol0 = blockIdx.x*64;          // hidden j cols (0..511)
    f32x4 acc[3][2][2];
    #pragma unroll
    for(int g=0;g<3;g++)
        #pragma unroll
        for(int i=0;i<2;i++)
            #pragma unroll
            for(int jj=0;jj<2;jj++) acc[g][i][jj]=(f32x4){0.f,0.f,0.f,0.f};
    for(int it=0; it<2; ++it){
        int kb = it*64;
        size_t aoff = (size_t)(row0+sr)*ZDIM + kb + sq;
        uint4 ah0 = *(const uint4*)(Zh + aoff);
        uint4 ah1 = *(const uint4*)(Zh + aoff + 8);
        uint4 al0 = *(const uint4*)(Zl + aoff);
        uint4 al1 = *(const uint4*)(Zl + aoff + 8);
        __syncthreads();        // prior frag reads complete
        *(uint4*)&AH[sr*72 + sq]     = ah0;
        *(uint4*)&AH[sr*72 + sq + 8] = ah1;
        *(uint4*)&AL[sr*72 + sq]     = al0;
        *(uint4*)&AL[sr*72 + sq + 8] = al1;
        for(int g=0; g<3; ++g){
            size_t boff = (size_t)(g*512 + jcol0 + sr)*ZDIM + kb + sq;
            uint4 bh0 = *(const uint4*)(Wid_h + boff);
            uint4 bh1 = *(const uint4*)(Wid_h + boff + 8);
            if(g>0) __syncthreads();    // prior gate done reading BH
            *(uint4*)&BH[sr*72 + sq]     = bh0;
            *(uint4*)&BH[sr*72 + sq + 8] = bh1;
            __syncthreads();
            #pragma unroll
            for(int ks=0; ks<2; ks++){
                int kk = ks*32 + kq;
                short8 a_h[2], a_l[2], b_h[2];
                #pragma unroll
                for(int mf=0;mf<2;mf++){
                    a_h[mf] = *(short8*)&AH[(m0+mf*16+fr)*72 + kk];
                    a_l[mf] = *(short8*)&AL[(m0+mf*16+fr)*72 + kk];
                }
                #pragma unroll
                for(int nf=0;nf<2;nf++)
                    b_h[nf] = *(short8*)&BH[(n0+nf*16+fr)*72 + kk];
                #pragma unroll
                for(int mf=0;mf<2;mf++)
                    #pragma unroll
                    for(int nf=0;nf<2;nf++){
                        acc[g][mf][nf] = __builtin_amdgcn_mfma_f32_16x16x32_bf16(a_h[mf], b_h[nf], acc[g][mf][nf], 0,0,0);
                        acc[g][mf][nf] = __builtin_amdgcn_mfma_f32_16x16x32_bf16(a_l[mf], b_h[nf], acc[g][mf][nf], 0,0,0);
                    }
            }
        }
    }
    // epilogue: GRU combine directly from accumulators
    int crow = (lane>>4)*4, ccol = lane&15;
    #pragma unroll
    for(int mf=0;mf<2;mf++)
        #pragma unroll
        for(int nf=0;nf<2;nf++)
            #pragma unroll
            for(int r=0;r<4;r++){
                int row = row0 + m0 + mf*16 + crow + r;     // batch
                int col = jcol0 + n0 + nf*16 + ccol;        // j
                size_t pbase = (size_t)row*G3 + col;
                float gi_r = acc[0][mf][nf][r] + bi[col];
                float gi_z = acc[1][mf][nf][r] + bi[512+col];
                float gi_n = acc[2][mf][nf][r] + bi[1024+col];
                float gh_r = Ph2[pbase]      + bh[col];
                float gh_z = Ph2[pbase+512]  + bh[512+col];
                float gh_n = Ph2[pbase+1024] + bh[1024+col];
                float rr = sigmoidf_(gi_r + gh_r);
                float zz = sigmoidf_(gi_z + gh_z);
                float nn = tanhf(gi_n + rr*gh_n);
                size_t idx = (size_t)row*HDIM + col;
                float hn = (1.f - zz)*nn + zz*h[idx];
                h[idx] = hn;
                ushort hh = f2bf_rne(hn);
                Hh[idx] = hh; Hl[idx] = f2bf_rne(hn - bf2f(hh));
            }
}

// write path: params+filterbank+reduce(Pw,4 slabs)+apply; refresh s_last; 512 threads
__global__ __launch_bounds__(512) void write_apply_k(const float* __restrict__ Pw, const float* __restrict__ b_wr,
        const float* __restrict__ hdec, const float* __restrict__ W_wa, const float* __restrict__ b_wa,
        float* __restrict__ rec, float* __restrict__ s_last){
    __shared__ float sFy[NGRID][ABDIM+1];
    __shared__ float sFx[NGRID][ABDIM+1];
    __shared__ float sw[NGRID][36];
    __shared__ float t[ABDIM][36];
    __shared__ float red5[40];
    __shared__ float pp[8];
    int bb = blockIdx.x, tid = threadIdx.x;
    const float* h = hdec + bb*HDIM;
    attn_params_dev512(h, W_wa, b_wa, red5, pp, tid);
    float invg = expf(-pp[4]);
    fill_fb_R(sFx, sFy, pp, tid);
    for(int i=tid;i<NGRID*NGRID;i+=512){
        float a = b_wr[i];
        #pragma unroll
        for(int s=0;s<4;s++) a += Pw[((size_t)s*BATCHN + bb)*1024 + i];
        sw[i>>5][i&31] = a;
    }
    __syncthreads();
    {
        int p = tid>>2, iq = tid&3;
        float a[8];
        #pragma unroll
        for(int i=0;i<8;i++) a[i]=0.f;
        for(int j=0;j<NGRID;j++){
            float fy = sFy[j][p];
            float4 w0 = *(const float4*)&sw[j][iq*8];
            float4 w1 = *(const float4*)&sw[j][iq*8+4];
            a[0]+=fy*w0.x; a[1]+=fy*w0.y; a[2]+=fy*w0.z; a[3]+=fy*w0.w;
            a[4]+=fy*w1.x; a[5]+=fy*w1.y; a[6]+=fy*w1.z; a[7]+=fy*w1.w;
        }
        float4 o0; o0.x=a[0];o0.y=a[1];o0.z=a[2];o0.w=a[3];
        float4 o1; o1.x=a[4];o1.y=a[5];o1.z=a[6];o1.w=a[7];
        *(float4*)&t[p][iq*8]   = o0;
        *(float4*)&t[p][iq*8+4] = o1;
    }
    __syncthreads();
    {
        int q = tid&127, pg = tid>>7;
        float fxc[32];
        #pragma unroll
        for(int i=0;i<32;i++) fxc[i] = sFx[i][q];
        for(int pi=0; pi<32; pi++){
            int p = pg*32 + pi;
            float acc = 0.f;
            #pragma unroll
            for(int i4=0;i4<8;i4++){
                float4 tv = *(const float4*)&t[p][i4*4];
                acc += tv.x*fxc[i4*4] + tv.y*fxc[i4*4+1] + tv.z*fxc[i4*4+2] + tv.w*fxc[i4*4+3];
            }
            size_t off = (size_t)bb*IMGSZ + p*ABDIM + q;
            float nv = rec[off] + acc*invg;
            rec[off] = nv;
            if(bb==BATCHN-1) s_last[p*ABDIM + q] = sigmoidf_(nv);
        }
    }
}

__global__ void sigmoid_all_k(float* __restrict__ rec){
    int i = blockIdx.x*256 + threadIdx.x;
    rec[i] = sigmoidf_(rec[i]);
}

extern "C" void kernel_launch(void* const* d_in, const int* in_sizes, int n_in,
                              void* d_out, int out_size, void* d_ws, size_t ws_size,
                              hipStream_t stream) {
    const float* x        = (const float*)d_in[0];
    const float* eps      = (const float*)d_in[1];
    const float* W_ih_enc = (const float*)d_in[2];
    const float* W_hh_enc = (const float*)d_in[3];
    const float* b_ih_enc = (const float*)d_in[4];
    const float* b_hh_enc = (const float*)d_in[5];
    const float* W_ih_dec = (const float*)d_in[6];
    const float* W_hh_dec = (const float*)d_in[7];
    const float* b_ih_dec = (const float*)d_in[8];
    const float* b_hh_dec = (const float*)d_in[9];
    const float* W_mu     = (const float*)d_in[10];
    const float* b_mu     = (const float*)d_in[11];
    const float* W_ls     = (const float*)d_in[12];
    const float* b_ls     = (const float*)d_in[13];
    const float* W_wr     = (const float*)d_in[14];
    const float* b_wr     = (const float*)d_in[15];
    const float* W_ra     = (const float*)d_in[16];
    const float* b_ra     = (const float*)d_in[17];
    const float* W_wa     = (const float*)d_in[18];
    const float* b_wa     = (const float*)d_in[19];

    float* rec = (float*)d_out;

    float* ws = (float*)d_ws;
    float* h_enc  = ws;  ws += BATCHN*HDIM;
    float* h_dec  = ws;  ws += BATCHN*HDIM;
    float* s_last = ws;  ws += IMGSZ;
    float* Pi     = ws;  ws += (size_t)4*SLAB;
    float* Ph     = ws;  ws += (size_t)SLAB;
    float* Ph2    = ws;  ws += (size_t)SLAB;
    float* Pw     = ws;  ws += (size_t)4*BATCHN*1024;

    ushort* us = (ushort*)ws;
    ushort* Wie_h = us; us += 1536*2560;
    ushort* Whe_h = us; us += 1536*512;
    ushort* Whd_h = us; us += 1536*512;
    ushort* Wid_h = us; us += 1536*128;
    ushort* Wwr_h = us; us += 1024*512;
    ushort* Eh    = us; us += BATCHN*ENCIN;
    ushort* El    = us; us += BATCHN*ENCIN;
    ushort* He_h  = us; us += BATCHN*HDIM;
    ushort* He_l  = us; us += BATCHN*HDIM;
    ushort* Hd_h  = us; us += BATCHN*HDIM;
    ushort* Hd_l  = us; us += BATCHN*HDIM;
    ushort* Zh    = us; us += BATCHN*ZDIM;
    ushort* Zl    = us; us += BATCHN*ZDIM;

    hipMemsetAsync(rec,   0, (size_t)BATCHN*IMGSZ*sizeof(float), stream);
    hipMemsetAsync(h_enc, 0, (size_t)BATCHN*HDIM*sizeof(float), stream);
    hipMemsetAsync(h_dec, 0, (size_t)BATCHN*HDIM*sizeof(float), stream);
    hipMemsetAsync(He_h,  0, (size_t)BATCHN*HDIM*sizeof(ushort)*2, stream);  // He_h+He_l contiguous
    hipMemsetAsync(Hd_h,  0, (size_t)BATCHN*HDIM*sizeof(ushort)*2, stream);  // Hd_h+Hd_l contiguous
    init_slast_k<<<IMGSZ/256,256,0,stream>>>(s_last);

    conv_wh_k<<<(1536*2560/4+255)/256,256,0,stream>>>(W_ih_enc, Wie_h, 1536*2560/4);
    conv_wh_k<<<(1536*512/4+255)/256,256,0,stream>>>(W_hh_enc, Whe_h, 1536*512/4);
    conv_wh_k<<<(1536*512/4+255)/256,256,0,stream>>>(W_hh_dec, Whd_h, 1536*512/4);
    conv_wh_k<<<(1536*128/4+255)/256,256,0,stream>>>(W_ih_dec, Wid_h, 1536*128/4);
    conv_wh_k<<<(1024*512/4+255)/256,256,0,stream>>>(W_wr, Wwr_h, 1024*512/4);

    for(int t=0;t<16;t++){
        read_attn_k<<<BATCHN,512,0,stream>>>(x, s_last, h_dec, Hd_h, Hd_l, W_ra, b_ra, Eh, El);
        gemm3_k<<<576,256,0,stream>>>(Eh, El, Wie_h, He_h, He_l, Whe_h,
                                      Hd_h, Hd_l, Whd_h, Pi, Ph, Ph2);
        combine_z_k<<<BATCHN,512,0,stream>>>(Pi, Ph, b_ih_enc, b_hh_enc,
            h_enc, He_h, He_l, W_mu, b_mu, W_ls, b_ls, eps + (size_t)t*BATCHN*ZDIM, Zh, Zl);
        deci_combine_k<<<dim3(8,4),256,0,stream>>>(Zh, Zl, Wid_h, Ph2,
            b_ih_dec, b_hh_dec, h_dec, Hd_h, Hd_l);
        gemm_wr_k<<<dim3(16,4,4),256,0,stream>>>(Hd_h, Hd_l, Wwr_h, Pw);
        write_apply_k<<<BATCHN,512,0,stream>>>(Pw, b_wr, h_dec, W_wa, b_wa, rec, s_last);
    }
    sigmoid_all_k<<<BATCHN*IMGSZ/256,256,0,stream>>>(rec);
}

// Round 10
// 1376.456 us; speedup vs baseline: 3.8339x; 1.0227x over previous
//
#include <hip/hip_runtime.h>
#include <math.h>

#define BATCHN 256
#define HDIM 512
#define ZDIM 128
#define NGRID 32
#define ABDIM 128
#define IMGSZ 16384   // 128*128
#define ENCIN 2560
#define G3 1536
#define SLAB (BATCHN*G3)

typedef __attribute__((ext_vector_type(8))) short short8;
typedef __attribute__((ext_vector_type(4))) float f32x4;

__device__ __forceinline__ float sigmoidf_(float x){ return 1.0f/(1.0f+expf(-x)); }

__device__ __forceinline__ ushort f2bf_rne(float f){
    union{float f; uint u;} x; x.f=f;
    uint r = (x.u + 0x7FFFu + ((x.u>>16)&1u)) >> 16;
    return (ushort)r;
}
__device__ __forceinline__ float bf2f(ushort h){
    union{uint u; float f;} y; y.u = ((uint)h)<<16;
    return y.f;
}

__global__ void init_slast_k(float* __restrict__ s_last){
    int i = blockIdx.x*256 + threadIdx.x;
    s_last[i] = 0.5f;   // sigmoid(0)
}

// convert f32 weights -> bf16 (hi only; 2-product scheme)
__global__ void conv_wh_k(const float* __restrict__ W, ushort* __restrict__ Wh, int n4){
    int i = blockIdx.x*256 + threadIdx.x;
    if(i>=n4) return;
    float4 v = ((const float4*)W)[i];
    ushort4 hv;
    hv.x=f2bf_rne(v.x); hv.y=f2bf_rne(v.y); hv.z=f2bf_rne(v.z); hv.w=f2bf_rne(v.w);
    ((ushort4*)Wh)[i] = hv;
}

// ---- swizzled async staging: 64 rows x 64 bf16 cols -> 8KB LDS (linear dest,
//      pre-swizzled global source; element (r,c) @ LDS r*128 + ((c>>3)^(r&7))*16 + (c&7)*2 )
__device__ __forceinline__ void stage_swz(const ushort* __restrict__ g, int K,
        int grow0, int kb, ushort* lds, int tid){
    int wv = tid>>6, lane = tid&63;
    #pragma unroll
    for(int q=0;q<2;q++){
        int instr = wv*2 + q;
        int rl = instr*8 + (lane>>3);
        int sc = (lane&7) ^ (lane>>3);
        const ushort* src = g + (size_t)(grow0+rl)*K + kb + sc*8;
        ushort* dst = lds + instr*512;     // wave-uniform; HW adds lane*16 bytes
        __builtin_amdgcn_global_load_lds((const __attribute__((address_space(1))) void*)src,
                                         (__attribute__((address_space(3))) void*)dst, 16, 0, 0);
    }
}

// read 8 bf16 at (row r, slot) from swizzled LDS tile
__device__ __forceinline__ short8 lds_read_swz(const ushort* arr, int r, int slot){
    return *(const short8*)&arr[r*64 + ((slot ^ (r&7))<<3)];
}

// ---- attention params with NT=512 threads ----
__device__ __forceinline__ void attn_params_dev512(const float* __restrict__ h,
        const float* __restrict__ W, const float* __restrict__ bvec,
        float* red5, float* pp, int tid){
    float accp[5];
    #pragma unroll
    for(int i=0;i<5;i++) accp[i]=0.f;
    for(int k=tid;k<HDIM;k+=512){
        float hv = h[k];
        #pragma unroll
        for(int i=0;i<5;i++) accp[i] += hv*W[i*HDIM+k];
    }
    int wv = tid>>6;
    #pragma unroll
    for(int i=0;i<5;i++){
        float a = accp[i];
        #pragma unroll
        for(int o=32;o>0;o>>=1) a += __shfl_down(a,o);
        if((tid&63)==0) red5[i*8+wv]=a;
    }
    __syncthreads();
    if(tid<5){
        float s = bvec[tid];
        #pragma unroll
        for(int w2=0;w2<8;w2++) s += red5[tid*8+w2];
        pp[tid]=s;
    }
    __syncthreads();
}

// transposed fill: fxT[pix][j], fyT[pix][j]; NT=512
__device__ __forceinline__ void fill_fb_T(float* fxT, float* fyT, const float* pp, int tid){
    float gx = 64.5f*(pp[0]+1.0f);
    float gy = 64.5f*(pp[1]+1.0f);
    float tss = 2.0f*expf(pp[2]);
    float delta = (127.0f/31.0f)*expf(pp[3]);
    int rr = tid>>3;
    int q  = tid&7;
    int j  = rr&31;
    bool isY = rr>=32;
    float mu = (isY?gy:gx) + ((float)j-15.5f)*delta;
    float v[16]; float s=0.f;
    #pragma unroll
    for(int i=0;i<16;i++){
        float d = (float)(q*16+i)-mu;
        float e = expf(-d*d/tss);
        v[i]=e; s+=e;
    }
    s += __shfl_xor(s,1); s += __shfl_xor(s,2); s += __shfl_xor(s,4);
    float inv = 1.0f/fmaxf(s,1e-8f);
    float* dst = isY? fyT : fxT;
    #pragma unroll
    for(int i=0;i<16;i++) dst[(q*16+i)*32 + j] = v[i]*inv;
    __syncthreads();
}

// row-major fill: fx[32][129], fy[32][129]; NT=512
__device__ __forceinline__ void fill_fb_R(float (*fx)[ABDIM+1], float (*fy)[ABDIM+1], const float* pp, int tid){
    float gx = 64.5f*(pp[0]+1.0f);
    float gy = 64.5f*(pp[1]+1.0f);
    float tss = 2.0f*expf(pp[2]);
    float delta = (127.0f/31.0f)*expf(pp[3]);
    int rr = tid>>3;
    int q  = tid&7;
    int j  = rr&31;
    bool isY = rr>=32;
    float mu = (isY?gy:gx) + ((float)j-15.5f)*delta;
    float v[16]; float s=0.f;
    #pragma unroll
    for(int i=0;i<16;i++){
        float d = (float)(q*16+i)-mu;
        float e = expf(-d*d/tss);
        v[i]=e; s+=e;
    }
    s += __shfl_xor(s,1); s += __shfl_xor(s,2); s += __shfl_xor(s,4);
    float inv = 1.0f/fmaxf(s,1e-8f);
    float* rowp = isY? &fy[j][0] : &fx[j][0];
    #pragma unroll
    for(int i=0;i<16;i++) rowp[q*16+i] = v[i]*inv;
    __syncthreads();
}

// per-batch fused read attention; 512 threads; writes enc_in as bf16 hi/lo
__global__ __launch_bounds__(512) void read_attn_k(const float* __restrict__ xf, const float* __restrict__ s_last,
        const float* __restrict__ hdec, const ushort* __restrict__ Hd_h, const ushort* __restrict__ Hd_l,
        const float* __restrict__ W_ra, const float* __restrict__ b_ra,
        ushort* __restrict__ Eh, ushort* __restrict__ El){
    __shared__ float smem[4096 + 8256 + 48];
    float* sFxT = smem;
    float* sFyT = smem + 4096;
    float* tmp  = smem + 4096;            // aliases sFyT (barrier-separated)
    float* red5 = smem + 4096 + 8256;
    float* pp   = red5 + 40;
    int bb = blockIdx.x; int tid = threadIdx.x;
    const float* h = hdec + bb*HDIM;
    attn_params_dev512(h, W_ra, b_ra, red5, pp, tid);
    float gamma = expf(pp[4]);
    fill_fb_T(sFxT, sFyT, pp, tid);

    const float* img = xf + (size_t)bb*IMGSZ;
    int c = tid & 127;
    int jg = tid >> 7;
    float acc0[8], accS[8];
    #pragma unroll
    for(int i=0;i<8;i++){ acc0[i]=0.f; accS[i]=0.f; }
    for(int k=0;k<ABDIM;k++){
        float s  = img[k*ABDIM + c];
        float sl = s_last[k*ABDIM + c];
        float4 f0 = *(const float4*)&sFyT[k*32 + jg*8];
        float4 f1 = *(const float4*)&sFyT[k*32 + jg*8 + 4];
        acc0[0]+=f0.x*s;  acc0[1]+=f0.y*s;  acc0[2]+=f0.z*s;  acc0[3]+=f0.w*s;
        acc0[4]+=f1.x*s;  acc0[5]+=f1.y*s;  acc0[6]+=f1.z*s;  acc0[7]+=f1.w*s;
        accS[0]+=f0.x*sl; accS[1]+=f0.y*sl; accS[2]+=f0.z*sl; accS[3]+=f0.w*sl;
        accS[4]+=f1.x*sl; accS[5]+=f1.y*sl; accS[6]+=f1.z*sl; accS[7]+=f1.w*sl;
    }
    __syncthreads();
    #pragma unroll
    for(int i=0;i<8;i++){
        int j = jg*8+i;
        tmp[0*32*129 + j*129 + c] = acc0[i];
        tmp[1*32*129 + j*129 + c] = acc0[i] - accS[i];
    }
    __syncthreads();
    {
        int i4 = tid & 7;
        int j  = (tid>>3) & 31;
        int p  = tid >> 8;
        float a0=0.f,a1=0.f,a2=0.f,a3=0.f;
        for(int cc=0; cc<ABDIM; cc++){
            float tv = tmp[p*32*129 + j*129 + cc];
            float4 fx = *(const float4*)&sFxT[cc*32 + i4*4];
            a0 += tv*fx.x; a1 += tv*fx.y; a2 += tv*fx.z; a3 += tv*fx.w;
        }
        float ov[4] = {gamma*a0, gamma*a1, gamma*a2, gamma*a3};
        ushort4 oh, ol; ushort hq;
        hq=f2bf_rne(ov[0]); oh.x=hq; ol.x=f2bf_rne(ov[0]-bf2f(hq));
        hq=f2bf_rne(ov[1]); oh.y=hq; ol.y=f2bf_rne(ov[1]-bf2f(hq));
        hq=f2bf_rne(ov[2]); oh.z=hq; ol.z=f2bf_rne(ov[2]-bf2f(hq));
        hq=f2bf_rne(ov[3]); oh.w=hq; ol.w=f2bf_rne(ov[3]-bf2f(hq));
        size_t off = (size_t)bb*ENCIN + p*1024 + j*NGRID + i4*4;
        *(ushort4*)(Eh + off) = oh;
        *(ushort4*)(El + off) = ol;
    }
    {
        int i = tid;
        Eh[(size_t)bb*ENCIN + 2048 + i] = Hd_h[(size_t)bb*HDIM + i];
        El[(size_t)bb*ENCIN + 2048 + i] = Hd_l[(size_t)bb*HDIM + i];
    }
}

// ---- one MFMA GEMM tile (2-product split-bf16), 64x64, 256thr, BK=64, gload_lds+swizzle ----
__device__ void gemm_one(const ushort* __restrict__ Agh, const ushort* __restrict__ Agl,
        const ushort* __restrict__ Wh,
        int K, int k0, int kiters, int row0, int col0, int Nn, float* __restrict__ Out,
        ushort* AH, ushort* AL, ushort* BH, int tid){
    int lane = tid&63, w = tid>>6;
    int m0 = (w>>1)*32, n0 = (w&1)*32;
    int fr = lane&15, sl = lane>>4;
    f32x4 acc[2][2];
    #pragma unroll
    for(int i=0;i<2;i++)
        #pragma unroll
        for(int j=0;j<2;j++) acc[i][j]=(f32x4){0.f,0.f,0.f,0.f};
    for(int it=0; it<kiters; ++it){
        int kb = k0 + it*64;
        stage_swz(Agh, K, row0, kb, AH, tid);
        stage_swz(Agl, K, row0, kb, AL, tid);
        stage_swz(Wh,  K, col0, kb, BH, tid);
        __syncthreads();                    // vmcnt(0) drained by compiler before barrier
        #pragma unroll
        for(int ks=0; ks<2; ks++){
            int slot = ks*4 + sl;
            short8 a_h[2], a_l[2], b_h[2];
            #pragma unroll
            for(int mf=0;mf<2;mf++){
                a_h[mf] = lds_read_swz(AH, m0+mf*16+fr, slot);
                a_l[mf] = lds_read_swz(AL, m0+mf*16+fr, slot);
            }
            #pragma unroll
            for(int nf=0;nf<2;nf++)
                b_h[nf] = lds_read_swz(BH, n0+nf*16+fr, slot);
            #pragma unroll
            for(int mf=0;mf<2;mf++)
                #pragma unroll
                for(int nf=0;nf<2;nf++){
                    acc[mf][nf] = __builtin_amdgcn_mfma_f32_16x16x32_bf16(a_h[mf], b_h[nf], acc[mf][nf], 0,0,0);
                    acc[mf][nf] = __builtin_amdgcn_mfma_f32_16x16x32_bf16(a_l[mf], b_h[nf], acc[mf][nf], 0,0,0);
                }
        }
        __syncthreads();                    // protect LDS from next iter's writes
    }
    int crow = (lane>>4)*4, ccol = lane&15;
    #pragma unroll
    for(int mf=0;mf<2;mf++)
        #pragma unroll
        for(int nf=0;nf<2;nf++)
            #pragma unroll
            for(int r=0;r<4;r++)
                Out[(size_t)(row0+m0+mf*16+crow+r)*Nn + col0+n0+nf*16+ccol] = acc[mf][nf][r];
}

// job pool: enc-i splitk4 (384 jobs @10 it) + enc-h (96 @8) + dec-h (96 @8) = 576 blocks
__global__ __launch_bounds__(256) void gemm3_k(
        const ushort* __restrict__ Eh, const ushort* __restrict__ El,
        const ushort* __restrict__ Wie_h,
        const ushort* __restrict__ He_h, const ushort* __restrict__ He_l,
        const ushort* __restrict__ Whe_h,
        const ushort* __restrict__ Hd_h, const ushort* __restrict__ Hd_l,
        const ushort* __restrict__ Whd_h,
        float* __restrict__ Pi, float* __restrict__ Ph, float* __restrict__ Ph2){
    __shared__ ushort AH[64*64], AL[64*64], BH[64*64];
    int job = blockIdx.x, tid = threadIdx.x;
    if(job < 384){
        int tile = job % 96, s = job / 96;
        gemm_one(Eh, El, Wie_h, ENCIN, s*640, 10,
                 (tile/24)*64, (tile%24)*64, G3, Pi + (size_t)s*SLAB, AH, AL, BH, tid);
    } else if(job < 480){
        int tile = job - 384;
        gemm_one(He_h, He_l, Whe_h, HDIM, 0, 8,
                 (tile/24)*64, (tile%24)*64, G3, Ph, AH, AL, BH, tid);
    } else {
        int tile = job - 480;
        gemm_one(Hd_h, Hd_l, Whd_h, HDIM, 0, 8,
                 (tile/24)*64, (tile%24)*64, G3, Ph2, AH, AL, BH, tid);
    }
}

// write GEMM: grid (16 cols, 4 rows, 4 splits), 64x64 tiles, K=512
__global__ __launch_bounds__(256) void gemm_wr_k(
        const ushort* __restrict__ Hd_h, const ushort* __restrict__ Hd_l,
        const ushort* __restrict__ Wwr_h,
        float* __restrict__ Pw){
    __shared__ ushort AH[64*64], AL[64*64], BH[64*64];
    int tid = threadIdx.x;
    int r0 = blockIdx.y*64, c0 = blockIdx.x*64, s = blockIdx.z;
    gemm_one(Hd_h, Hd_l, Wwr_h, HDIM, s*128, 2, r0, c0, 1024,
             Pw + (size_t)s*BATCHN*1024, AH, AL, BH, tid);
}

// encoder combine (4 Pi + 1 Ph) + z sample -> Zh/Zl mirrors
__global__ __launch_bounds__(512) void combine_z_k(const float* __restrict__ Pi, const float* __restrict__ Ph,
        const float* __restrict__ bi, const float* __restrict__ bh,
        float* __restrict__ h, ushort* __restrict__ Hh, ushort* __restrict__ Hl,
        const float* __restrict__ Wmu, const float* __restrict__ bmu,
        const float* __restrict__ Wls, const float* __restrict__ bls,
        const float* __restrict__ eps_t, ushort* __restrict__ Zh, ushort* __restrict__ Zl){
    __shared__ float hs[HDIM];
    int bb = blockIdx.x, tid = threadIdx.x;
    int j = tid;
    float gi_r=bi[j], gi_z=bi[512+j], gi_n=bi[1024+j];
    float gh_r=bh[j], gh_z=bh[512+j], gh_n=bh[1024+j];
    #pragma unroll
    for(int s=0;s<4;s++){
        size_t base = (size_t)s*SLAB + (size_t)bb*G3 + j;
        gi_r += Pi[base]; gi_z += Pi[base+512]; gi_n += Pi[base+1024];
    }
    {
        size_t base = (size_t)bb*G3 + j;
        gh_r += Ph[base]; gh_z += Ph[base+512]; gh_n += Ph[base+1024];
    }
    float r = sigmoidf_(gi_r + gh_r);
    float z = sigmoidf_(gi_z + gh_z);
    float n = tanhf(gi_n + r*gh_n);
    size_t hoff = (size_t)bb*HDIM + j;
    float hn = (1.f - z)*n + z*h[hoff];
    h[hoff] = hn; hs[j] = hn;
    ushort hh = f2bf_rne(hn);
    Hh[hoff] = hh; Hl[hoff] = f2bf_rne(hn - bf2f(hh));
    __syncthreads();
    // z sample: wave per output; lane reads 32B contiguous of each weight row (coalesced)
    {
        int wv = tid>>6, lane = tid&63;
        const float4* hs4 = (const float4*)hs;
        float4 h0 = hs4[lane*2];
        float4 h1 = hs4[lane*2+1];
        #pragma unroll 4
        for(int it=0; it<16; ++it){
            int jo = wv*16 + it;
            const float4* wm = (const float4*)(Wmu + (size_t)jo*HDIM);
            const float4* wl = (const float4*)(Wls + (size_t)jo*HDIM);
            float4 m0=wm[lane*2], m1=wm[lane*2+1];
            float4 l0=wl[lane*2], l1=wl[lane*2+1];
            float am  = h0.x*m0.x+h0.y*m0.y+h0.z*m0.z+h0.w*m0.w
                      + h1.x*m1.x+h1.y*m1.y+h1.z*m1.z+h1.w*m1.w;
            float al_ = h0.x*l0.x+h0.y*l0.y+h0.z*l0.z+h0.w*l0.w
                      + h1.x*l1.x+h1.y*l1.y+h1.z*l1.z+h1.w*l1.w;
            #pragma unroll
            for(int o=32;o>0;o>>=1){ am += __shfl_down(am,o); al_ += __shfl_down(al_,o); }
            if(lane==0){
                float mu = am + bmu[jo];
                float sg = expf(al_ + bls[jo]);
                float zv = mu + eps_t[(size_t)bb*ZDIM + jo]*sg;
                ushort zh = f2bf_rne(zv);
                Zh[(size_t)bb*ZDIM + jo] = zh;
                Zl[(size_t)bb*ZDIM + jo] = f2bf_rne(zv - bf2f(zh));
            }
        }
    }
}

// dec-i MFMA (Z @ Wid^T, gates r/z/n) fused with decoder GRU combine; 2-product
// grid (8 j-col-groups, 4 batch-row-groups); 256 thr
__global__ __launch_bounds__(256) void deci_combine_k(
        const ushort* __restrict__ Zh, const ushort* __restrict__ Zl,
        const ushort* __restrict__ Wid_h,
        const float* __restrict__ Ph2, const float* __restrict__ bi, const float* __restrict__ bh,
        float* __restrict__ h, ushort* __restrict__ Hh, ushort* __restrict__ Hl){
    __shared__ ushort AH[64*64], AL[64*64], BH[64*64];
    int tid = threadIdx.x;
    int lane = tid&63, w = tid>>6;
    int m0 = (w>>1)*32, n0 = (w&1)*32;
    int fr = lane&15, sl = lane>>4;
    int row0 = blockIdx.y*64;           // batch rows
    int jcol0 = blockIdx.x*64;          // hidden j cols (0..511)
    f32x4 acc[3][2][2];
    #pragma unroll
    for(int g=0;g<3;g++)
        #pragma unroll
        for(int i=0;i<2;i++)
            #pragma unroll
            for(int jj=0;jj<2;jj++) acc[g][i][jj]=(f32x4){0.f,0.f,0.f,0.f};
    for(int it=0; it<2; ++it){
        int kb = it*64;
        stage_swz(Zh, ZDIM, row0, kb, AH, tid);
        stage_swz(Zl, ZDIM, row0, kb, AL, tid);
        for(int g=0; g<3; ++g){
            stage_swz(Wid_h, ZDIM, g*512 + jcol0, kb, BH, tid);
            __syncthreads();            // drains all outstanding gload_lds (A on g=0, B always)
            #pragma unroll
            for(int ks=0; ks<2; ks++){
                int slot = ks*4 + sl;
                short8 a_h[2], a_l[2], b_h[2];
                #pragma unroll
                for(int mf=0;mf<2;mf++){
                    a_h[mf] = lds_read_swz(AH, m0+mf*16+fr, slot);
                    a_l[mf] = lds_read_swz(AL, m0+mf*16+fr, slot);
                }
                #pragma unroll
                for(int nf=0;nf<2;nf++)
                    b_h[nf] = lds_read_swz(BH, n0+nf*16+fr, slot);
                #pragma unroll
                for(int mf=0;mf<2;mf++)
                    #pragma unroll
                    for(int nf=0;nf<2;nf++){
                        acc[g][mf][nf] = __builtin_amdgcn_mfma_f32_16x16x32_bf16(a_h[mf], b_h[nf], acc[g][mf][nf], 0,0,0);
                        acc[g][mf][nf] = __builtin_amdgcn_mfma_f32_16x16x32_bf16(a_l[mf], b_h[nf], acc[g][mf][nf], 0,0,0);
                    }
            }
            __syncthreads();            // all waves done reading BH before next gate's writes
        }
    }
    // epilogue: GRU combine directly from accumulators
    int crow = (lane>>4)*4, ccol = lane&15;
    #pragma unroll
    for(int mf=0;mf<2;mf++)
        #pragma unroll
        for(int nf=0;nf<2;nf++)
            #pragma unroll
            for(int r=0;r<4;r++){
                int row = row0 + m0 + mf*16 + crow + r;     // batch
                int col = jcol0 + n0 + nf*16 + ccol;        // j
                size_t pbase = (size_t)row*G3 + col;
                float gi_r = acc[0][mf][nf][r] + bi[col];
                float gi_z = acc[1][mf][nf][r] + bi[512+col];
                float gi_n = acc[2][mf][nf][r] + bi[1024+col];
                float gh_r = Ph2[pbase]      + bh[col];
                float gh_z = Ph2[pbase+512]  + bh[512+col];
                float gh_n = Ph2[pbase+1024] + bh[1024+col];
                float rr = sigmoidf_(gi_r + gh_r);
                float zz = sigmoidf_(gi_z + gh_z);
                float nn = tanhf(gi_n + rr*gh_n);
                size_t idx = (size_t)row*HDIM + col;
                float hn = (1.f - zz)*nn + zz*h[idx];
                h[idx] = hn;
                ushort hh = f2bf_rne(hn);
                Hh[idx] = hh; Hl[idx] = f2bf_rne(hn - bf2f(hh));
            }
}

// write path: params+filterbank+reduce(Pw,4 slabs)+apply; refresh s_last; 512 threads
// last!=0: apply final sigmoid to rec (replaces sigmoid_all_k)
__global__ __launch_bounds__(512) void write_apply_k(const float* __restrict__ Pw, const float* __restrict__ b_wr,
        const float* __restrict__ hdec, const float* __restrict__ W_wa, const float* __restrict__ b_wa,
        float* __restrict__ rec, float* __restrict__ s_last, int last){
    __shared__ float sFy[NGRID][ABDIM+1];
    __shared__ float sFx[NGRID][ABDIM+1];
    __shared__ float sw[NGRID][36];
    __shared__ float t[ABDIM][36];
    __shared__ float red5[40];
    __shared__ float pp[8];
    int bb = blockIdx.x, tid = threadIdx.x;
    const float* h = hdec + bb*HDIM;
    attn_params_dev512(h, W_wa, b_wa, red5, pp, tid);
    float invg = expf(-pp[4]);
    fill_fb_R(sFx, sFy, pp, tid);
    for(int i=tid;i<NGRID*NGRID;i+=512){
        float a = b_wr[i];
        #pragma unroll
        for(int s=0;s<4;s++) a += Pw[((size_t)s*BATCHN + bb)*1024 + i];
        sw[i>>5][i&31] = a;
    }
    __syncthreads();
    {
        int p = tid>>2, iq = tid&3;
        float a[8];
        #pragma unroll
        for(int i=0;i<8;i++) a[i]=0.f;
        for(int j=0;j<NGRID;j++){
            float fy = sFy[j][p];
            float4 w0 = *(const float4*)&sw[j][iq*8];
            float4 w1 = *(const float4*)&sw[j][iq*8+4];
            a[0]+=fy*w0.x; a[1]+=fy*w0.y; a[2]+=fy*w0.z; a[3]+=fy*w0.w;
            a[4]+=fy*w1.x; a[5]+=fy*w1.y; a[6]+=fy*w1.z; a[7]+=fy*w1.w;
        }
        float4 o0; o0.x=a[0];o0.y=a[1];o0.z=a[2];o0.w=a[3];
        float4 o1; o1.x=a[4];o1.y=a[5];o1.z=a[6];o1.w=a[7];
        *(float4*)&t[p][iq*8]   = o0;
        *(float4*)&t[p][iq*8+4] = o1;
    }
    __syncthreads();
    {
        int q = tid&127, pg = tid>>7;
        float fxc[32];
        #pragma unroll
        for(int i=0;i<32;i++) fxc[i] = sFx[i][q];
        for(int pi=0; pi<32; pi++){
            int p = pg*32 + pi;
            float acc = 0.f;
            #pragma unroll
            for(int i4=0;i4<8;i4++){
                float4 tv = *(const float4*)&t[p][i4*4];
                acc += tv.x*fxc[i4*4] + tv.y*fxc[i4*4+1] + tv.z*fxc[i4*4+2] + tv.w*fxc[i4*4+3];
            }
            size_t off = (size_t)bb*IMGSZ + p*ABDIM + q;
            float nv = rec[off] + acc*invg;
            rec[off] = last ? sigmoidf_(nv) : nv;
            if(bb==BATCHN-1) s_last[p*ABDIM + q] = sigmoidf_(nv);
        }
    }
}

extern "C" void kernel_launch(void* const* d_in, const int* in_sizes, int n_in,
                              void* d_out, int out_size, void* d_ws, size_t ws_size,
                              hipStream_t stream) {
    const float* x        = (const float*)d_in[0];
    const float* eps      = (const float*)d_in[1];
    const float* W_ih_enc = (const float*)d_in[2];
    const float* W_hh_enc = (const float*)d_in[3];
    const float* b_ih_enc = (const float*)d_in[4];
    const float* b_hh_enc = (const float*)d_in[5];
    const float* W_ih_dec = (const float*)d_in[6];
    const float* W_hh_dec = (const float*)d_in[7];
    const float* b_ih_dec = (const float*)d_in[8];
    const float* b_hh_dec = (const float*)d_in[9];
    const float* W_mu     = (const float*)d_in[10];
    const float* b_mu     = (const float*)d_in[11];
    const float* W_ls     = (const float*)d_in[12];
    const float* b_ls     = (const float*)d_in[13];
    const float* W_wr     = (const float*)d_in[14];
    const float* b_wr     = (const float*)d_in[15];
    const float* W_ra     = (const float*)d_in[16];
    const float* b_ra     = (const float*)d_in[17];
    const float* W_wa     = (const float*)d_in[18];
    const float* b_wa     = (const float*)d_in[19];

    float* rec = (float*)d_out;

    float* ws = (float*)d_ws;
    float* h_enc  = ws;  ws += BATCHN*HDIM;
    float* h_dec  = ws;  ws += BATCHN*HDIM;
    float* s_last = ws;  ws += IMGSZ;
    float* Pi     = ws;  ws += (size_t)4*SLAB;
    float* Ph     = ws;  ws += (size_t)SLAB;
    float* Ph2    = ws;  ws += (size_t)SLAB;
    float* Pw     = ws;  ws += (size_t)4*BATCHN*1024;

    ushort* us = (ushort*)ws;
    ushort* Wie_h = us; us += 1536*2560;
    ushort* Whe_h = us; us += 1536*512;
    ushort* Whd_h = us; us += 1536*512;
    ushort* Wid_h = us; us += 1536*128;
    ushort* Wwr_h = us; us += 1024*512;
    ushort* Eh    = us; us += BATCHN*ENCIN;
    ushort* El    = us; us += BATCHN*ENCIN;
    ushort* He_h  = us; us += BATCHN*HDIM;
    ushort* He_l  = us; us += BATCHN*HDIM;
    ushort* Hd_h  = us; us += BATCHN*HDIM;
    ushort* Hd_l  = us; us += BATCHN*HDIM;
    ushort* Zh    = us; us += BATCHN*ZDIM;
    ushort* Zl    = us; us += BATCHN*ZDIM;

    hipMemsetAsync(rec,   0, (size_t)BATCHN*IMGSZ*sizeof(float), stream);
    hipMemsetAsync(h_enc, 0, (size_t)BATCHN*HDIM*sizeof(float), stream);
    hipMemsetAsync(h_dec, 0, (size_t)BATCHN*HDIM*sizeof(float), stream);
    hipMemsetAsync(He_h,  0, (size_t)BATCHN*HDIM*sizeof(ushort)*2, stream);  // He_h+He_l contiguous
    hipMemsetAsync(Hd_h,  0, (size_t)BATCHN*HDIM*sizeof(ushort)*2, stream);  // Hd_h+Hd_l contiguous
    init_slast_k<<<IMGSZ/256,256,0,stream>>>(s_last);

    conv_wh_k<<<(1536*2560/4+255)/256,256,0,stream>>>(W_ih_enc, Wie_h, 1536*2560/4);
    conv_wh_k<<<(1536*512/4+255)/256,256,0,stream>>>(W_hh_enc, Whe_h, 1536*512/4);
    conv_wh_k<<<(1536*512/4+255)/256,256,0,stream>>>(W_hh_dec, Whd_h, 1536*512/4);
    conv_wh_k<<<(1536*128/4+255)/256,256,0,stream>>>(W_ih_dec, Wid_h, 1536*128/4);
    conv_wh_k<<<(1024*512/4+255)/256,256,0,stream>>>(W_wr, Wwr_h, 1024*512/4);

    for(int t=0;t<16;t++){
        read_attn_k<<<BATCHN,512,0,stream>>>(x, s_last, h_dec, Hd_h, Hd_l, W_ra, b_ra, Eh, El);
        gemm3_k<<<576,256,0,stream>>>(Eh, El, Wie_h, He_h, He_l, Whe_h,
                                      Hd_h, Hd_l, Whd_h, Pi, Ph, Ph2);
        combine_z_k<<<BATCHN,512,0,stream>>>(Pi, Ph, b_ih_enc, b_hh_enc,
            h_enc, He_h, He_l, W_mu, b_mu, W_ls, b_ls, eps + (size_t)t*BATCHN*ZDIM, Zh, Zl);
        deci_combine_k<<<dim3(8,4),256,0,stream>>>(Zh, Zl, Wid_h, Ph2,
            b_ih_dec, b_hh_dec, h_dec, Hd_h, Hd_l);
        gemm_wr_k<<<dim3(16,4,4),256,0,stream>>>(Hd_h, Hd_l, Wwr_h, Pw);
        write_apply_k<<<BATCHN,512,0,stream>>>(Pw, b_wr, h_dec, W_wa, b_wa, rec, s_last,
                                               (t==15)?1:0);
    }
}